// Round 4
// baseline (279.236 us; speedup 1.0000x reference)
//
#include <hip/hip_runtime.h>
#include <math.h>

#define NN 20000
#define NE 320000
#define F 128
#define NLAYER 3
#define MPAD 20032          // 313 * 64
#define CATW 768            // [x | mean sum std min max]

typedef unsigned int u32;
typedef unsigned short u16;
typedef __attribute__((ext_vector_type(8))) short bf16x8;
typedef __attribute__((ext_vector_type(4))) float f32x4;

__device__ __forceinline__ u16 f2bf(float f) {
    union { float f; u32 u; } x{f};
    u32 r = x.u + 0x7FFFu + ((x.u >> 16) & 1u);
    return (u16)(r >> 16);
}
__device__ __forceinline__ float bflo(u32 u) { return __uint_as_float(u << 16); }
__device__ __forceinline__ float bfhi(u32 u) { return __uint_as_float(u & 0xFFFF0000u); }

__device__ __forceinline__ void gload16(const u16* g, u16* l) {
    __builtin_amdgcn_global_load_lds(
        (const __attribute__((address_space(1))) void*)g,
        (__attribute__((address_space(3))) void*)l, 16, 0, 0);
}

// ---------------- graph-structure kernels ----------------

__global__ void zero_ints_kernel(int* __restrict__ a, int* __restrict__ b, int n) {
    int i = blockIdx.x * blockDim.x + threadIdx.x;
    if (i < n) { a[i] = 0; b[i] = 0; }
}

__global__ void hist_kernel(const int* __restrict__ dst, int* __restrict__ cnt, int e) {
    int i = blockIdx.x * blockDim.x + threadIdx.x;
    if (i < e) atomicAdd(&cnt[dst[i]], 1);
}

// exclusive scan + degree scalers fused
__global__ void scan_kernel(const int* __restrict__ cnt, int* __restrict__ off,
                            float* __restrict__ amp, float* __restrict__ att,
                            float avg_log, int n) {
    __shared__ int sums[1024];
    int tid = threadIdx.x;
    int chunk = (n + 1023) >> 10;
    int b0 = tid * chunk;
    int b1 = min(b0 + chunk, n);
    int s = 0;
    for (int i = b0; i < b1; ++i) s += cnt[i];
    sums[tid] = s;
    __syncthreads();
    for (int d = 1; d < 1024; d <<= 1) {
        int v = (tid >= d) ? sums[tid - d] : 0;
        __syncthreads();
        sums[tid] += v;
        __syncthreads();
    }
    int pre = (tid == 0) ? 0 : sums[tid - 1];
    for (int i = b0; i < b1; ++i) {
        off[i] = pre; pre += cnt[i];
        float deg = fmaxf((float)cnt[i], 1.0f);
        float ld = logf(deg + 1.0f);
        amp[i] = ld / avg_log;
        att[i] = avg_log / ld;
    }
    if (tid == 1023) off[n] = pre;
}

__global__ void scatter_kernel(const int* __restrict__ src, const int* __restrict__ dst,
                               const int* __restrict__ off, int* __restrict__ cur,
                               int* __restrict__ csr, int e) {
    int i = blockIdx.x * blockDim.x + threadIdx.x;
    if (i < e) {
        int d = dst[i];
        int p = atomicAdd(&cur[d], 1);
        csr[off[d] + p] = src[i];
    }
}

// ---------------- combined prep: converts + biases, flat-indexed ----------------

#define P0 2560000L                 // xprep NN*F
#define P1 (P0 + 3L * 256 * 128)    // wpreT
#define P2 (P1 + 3L * 128 * 128)    // wlinT
#define P3 (P2 + 3L * 2048 * 128)   // wpost
#define P4 (P3 + 3L * 256)          // biaspre
#define P5 (P4 + 3L * 128)          // bcomb

__global__ void prep_all(const float* __restrict__ x, const float* __restrict__ W_pre,
                         const float* __restrict__ W_lin, const float* __restrict__ W_post,
                         const float* __restrict__ b_pre, const float* __restrict__ b_post,
                         const float* __restrict__ b_lin,
                         u16* __restrict__ xbuf, u16* __restrict__ cat,
                         u16* __restrict__ WpreT, u16* __restrict__ WlinT,
                         u16* __restrict__ Wpostb, float* __restrict__ biaspre,
                         float* __restrict__ bcomb) {
    long i = (long)blockIdx.x * 256 + threadIdx.x;
    if (i < P0) {
        u16 h = f2bf(x[i]);
        xbuf[i] = h;
        cat[(size_t)(i >> 7) * CATW + (i & 127)] = h;
    } else if (i < P1) {
        long j = i - P0;
        int l = j / 32768, t = j % 32768;
        int c = t >> 7, k = t & 127;
        int si = (c < 128) ? (k * 128 + c) : ((k + 128) * 128 + (c - 128));
        WpreT[l * 32768 + t] = f2bf(W_pre[l * 32768 + si]);
    } else if (i < P2) {
        long j = i - P1;
        int l = j / 16384, t = j % 16384;
        int c = t >> 7, k = t & 127;
        WlinT[l * 16384 + t] = f2bf(W_lin[l * 16384 + k * 128 + c]);
    } else if (i < P3) {
        long j = i - P2;
        Wpostb[j] = f2bf(W_post[j]);
    } else if (i < P4) {
        long j = i - P3;
        int l = j / 256, t = j % 256;
        biaspre[l * 256 + t] = (t < 128) ? b_pre[l * 128 + t] : 0.f;
    } else if (i < P5) {
        long j = i - P4;
        int l = j / 128, t = j % 128;
        float s = b_lin[l * 128 + t];
        for (int c = 0; c < 128; ++c) s += b_post[l * 128 + c] * W_lin[l * 16384 + c * 128 + t];
        bcomb[l * 128 + t] = s;
    }
}

// BtK[l][row=g*128+j][k 768]
__global__ void brepack_kernel(const u16* __restrict__ Btcomb, u16* __restrict__ out) {
    int l = blockIdx.y;
    int i = blockIdx.x * 256 + threadIdx.x;   // 384*768
    if (i >= 384 * 768) return;
    int rho = i / 768, k = i % 768;
    int g = rho >> 7, j = rho & 127;
    const u16* B = Btcomb + (size_t)l * 262144;
    u16 v;
    if (k < 128) v = (g == 0) ? B[j * 2048 + k] : (u16)0;
    else         v = B[j * 2048 + 128 + g * 640 + (k - 128)];
    out[(size_t)l * 294912 + i] = v;
}

// ---------------- aggregation: one wave per node, int4 CSR + 4 gathers in flight ----------------

#define PROC(u) { float v_; \
    v_ = bflo(u); s0 += v_; q0 = fmaf(v_, v_, q0); mn0 = fminf(mn0, v_); mx0 = fmaxf(mx0, v_); \
    v_ = bfhi(u); s1 += v_; q1 = fmaf(v_, v_, q1); mn1 = fminf(mn1, v_); mx1 = fmaxf(mx1, v_); }

__global__ void agg_kernel(const u16* __restrict__ preout, const int* __restrict__ off,
                           const int* __restrict__ csr, u16* __restrict__ cat) {
    int gid = blockIdx.x * blockDim.x + threadIdx.x;
    int node = gid >> 6, lane = threadIdx.x & 63;
    if (node >= NN) return;
    int o0 = off[node], o1 = off[node + 1];
    const u32* bpl = (const u32*)preout + 64 + lane;   // row stride 128 u32
    float s0 = 0, s1 = 0, q0 = 0, q1 = 0;
    float mn0 = 1e30f, mn1 = 1e30f, mx0 = -1e30f, mx1 = -1e30f;
    int j = o0;
    while (j < o1 && (j & 3)) { u32 u = bpl[(size_t)csr[j] * 128]; PROC(u); ++j; }
    int nq = (o1 - j) >> 2;
    if (nq > 0) {
        int4 idx = *(const int4*)&csr[j];
        for (int q = 1; q < nq; ++q) {
            int4 nxt = *(const int4*)&csr[j + 4 * q];
            u32 u0 = bpl[(size_t)idx.x * 128];
            u32 u1 = bpl[(size_t)idx.y * 128];
            u32 u2 = bpl[(size_t)idx.z * 128];
            u32 u3 = bpl[(size_t)idx.w * 128];
            PROC(u0); PROC(u1); PROC(u2); PROC(u3);
            idx = nxt;
        }
        u32 u0 = bpl[(size_t)idx.x * 128];
        u32 u1 = bpl[(size_t)idx.y * 128];
        u32 u2 = bpl[(size_t)idx.z * 128];
        u32 u3 = bpl[(size_t)idx.w * 128];
        PROC(u0); PROC(u1); PROC(u2); PROC(u3);
        j += nq * 4;
    }
    while (j < o1) { u32 u = bpl[(size_t)csr[j] * 128]; PROC(u); ++j; }

    int degi = o1 - o0;
    float mean0, mean1, sum0, sum1, std0, std1, lo0, lo1, hi0, hi1;
    if (degi == 0) {
        sum0 = sum1 = 0.f; mean0 = mean1 = 0.f;
        std0 = std1 = sqrtf(1e-5f);
        lo0 = lo1 = hi0 = hi1 = 0.f;
    } else {
        u32 uc = ((const u32*)preout)[(size_t)node * 128 + lane];
        float c0 = bflo(uc), c1 = bfhi(uc), dg = (float)degi;
        sum0 = dg * c0 + s0; mean0 = sum0 / dg;
        sum1 = dg * c1 + s1; mean1 = sum1 / dg;
        float msq0 = c0 * c0 + (2.f * c0 * s0 + q0) / dg;
        float msq1 = c1 * c1 + (2.f * c1 * s1 + q1) / dg;
        std0 = sqrtf(fmaxf(msq0 - mean0 * mean0, 0.f) + 1e-5f);
        std1 = sqrtf(fmaxf(msq1 - mean1 * mean1, 0.f) + 1e-5f);
        lo0 = c0 + mn0; lo1 = c1 + mn1; hi0 = c0 + mx0; hi1 = c1 + mx1;
    }
    u32* cr = (u32*)cat + (size_t)node * (CATW / 2) + 64 + lane;
    float f0[5] = {mean0, sum0, std0, lo0, hi0};
    float f1[5] = {mean1, sum1, std1, lo1, hi1};
#pragma unroll
    for (int a = 0; a < 5; ++a)
        cr[a * 64] = (u32)f2bf(f0[a]) | ((u32)f2bf(f1[a]) << 16);
}

// ---------------- generic bf16 MFMA GEMM (layer-0 pre + weight-product) ----------------

template <bool BIAS>
__global__ __launch_bounds__(256) void mfma_gemm(
    const u16* __restrict__ A, int lda,
    const u16* __restrict__ Bt, int K,
    const float* __restrict__ bias,
    u16* __restrict__ C, int ldc, int Mreal,
    size_t aS, size_t bS, size_t cS) {
    __shared__ u16 As[64 * 32];
    __shared__ u16 Bs[128 * 32];
    int z = blockIdx.z;
    A += (size_t)z * aS; Bt += (size_t)z * bS; C += (size_t)z * cS;
    int tid = threadIdx.x;
    int w = tid >> 6, lane = tid & 63;
    int row0 = blockIdx.x * 64, col0 = blockIdx.y * 128;

    int arow = tid >> 2, asl = tid & 3;
    const u16* agp = A + (size_t)(row0 + arow) * lda + ((asl ^ ((arow >> 1) & 3)) << 3);
    u16* alds = As + w * 512;
    int br0 = tid >> 2;
    int br1 = 64 + (tid >> 2);
    const u16* bgp0 = Bt + (size_t)(col0 + br0) * K + (((tid & 3) ^ ((br0 >> 1) & 3)) << 3);
    const u16* bgp1 = Bt + (size_t)(col0 + br1) * K + (((tid & 3) ^ ((br1 >> 1) & 3)) << 3);
    u16* blds0 = Bs + w * 512;
    u16* blds1 = Bs + 2048 + w * 512;

    f32x4 acc[2][4];
#pragma unroll
    for (int m = 0; m < 2; ++m)
#pragma unroll
        for (int n = 0; n < 4; ++n) acc[m][n] = (f32x4){0.f, 0.f, 0.f, 0.f};

    int s = lane >> 4, r = lane & 15;
    int wr = (w >> 1) * 32, wc = (w & 1) * 64;

    for (int k0 = 0; k0 < K; k0 += 32) {
        gload16(agp + k0, alds);
        gload16(bgp0 + k0, blds0);
        gload16(bgp1 + k0, blds1);
        __syncthreads();
        bf16x8 a[2], b[4];
#pragma unroll
        for (int m = 0; m < 2; ++m) {
            int row = wr + m * 16 + r;
            a[m] = *(const bf16x8*)&As[row * 32 + ((s ^ ((row >> 1) & 3)) << 3)];
        }
#pragma unroll
        for (int n = 0; n < 4; ++n) {
            int col = wc + n * 16 + r;
            b[n] = *(const bf16x8*)&Bs[col * 32 + ((s ^ ((col >> 1) & 3)) << 3)];
        }
#pragma unroll
        for (int m = 0; m < 2; ++m)
#pragma unroll
            for (int n = 0; n < 4; ++n)
                acc[m][n] = __builtin_amdgcn_mfma_f32_16x16x32_bf16(a[m], b[n], acc[m][n], 0, 0, 0);
        __syncthreads();
    }

#pragma unroll
    for (int m = 0; m < 2; ++m) {
#pragma unroll
        for (int n = 0; n < 4; ++n) {
            int gcol = col0 + wc + n * 16 + r;
            float bs = BIAS ? bias[gcol] : 0.f;
#pragma unroll
            for (int j = 0; j < 4; ++j) {
                int grow = row0 + wr + m * 16 + s * 4 + j;
                if (grow < Mreal)
                    C[(size_t)grow * ldc + gcol] = f2bf(acc[m][n][j] + bs);
            }
        }
    }
}

// ---------------- fused comb GEMM (+ optional pre_nn for next layer) ----------------
// 512 threads (8 waves), tile 64 rows x 128 out cols, B = BtK [384][768]
// phase 2 (PRE): x-tile in LDS @ 0, Wp [256][64-step] staged @ u16 offset 8192

template <bool PRE>
__global__ __launch_bounds__(512) void fused_comb(
    const u16* __restrict__ A,          // cat [MPAD][768]
    const u16* __restrict__ BtK,        // [384][768]
    const float* __restrict__ bias,     // bcomb 128
    const float* __restrict__ amp, const float* __restrict__ att,   // MPAD
    const u16* __restrict__ Wp,         // WpreT next layer [256][128]
    const float* __restrict__ bias2,    // biaspre next layer [256]
    u16* __restrict__ xout,             // xbuf [MPAD][128]
    u16* __restrict__ catout,           // cat cols 0..127
    u16* __restrict__ preout) {         // [MPAD][256]
    __shared__ u16 S[448 * 64];         // 56 KB
    int tid = threadIdx.x;
    int row0 = blockIdx.x * 64;
    int w = tid >> 6, lane = tid & 63;
    int r = lane & 15, s = lane >> 4;
    int wr = (w >> 2) * 32, wc = (w & 3) * 32;

    const u16* gp[7];
#pragma unroll
    for (int p = 0; p < 7; ++p) {
        int lid = tid + 512 * p;
        int row = lid >> 3, sl = lid & 7;
        int koff = (sl ^ (row & 7)) << 3;
        gp[p] = (row < 64) ? A + (size_t)(row0 + row) * 768 + koff
                           : BtK + (size_t)(row - 64) * 768 + koff;
    }

    f32x4 acc[2][3][2];
#pragma unroll
    for (int m = 0; m < 2; ++m)
#pragma unroll
        for (int g = 0; g < 3; ++g)
#pragma unroll
            for (int n = 0; n < 2; ++n) acc[m][g][n] = (f32x4){0.f, 0.f, 0.f, 0.f};

    for (int k0 = 0; k0 < 768; k0 += 64) {
#pragma unroll
        for (int p = 0; p < 7; ++p)
            gload16(gp[p] + k0, S + (size_t)(tid + 512 * p) * 8);
        __syncthreads();
#pragma unroll
        for (int kk = 0; kk < 2; ++kk) {
            int cs = kk * 4 + s;
            bf16x8 a[2];
#pragma unroll
            for (int m = 0; m < 2; ++m) {
                int row = wr + m * 16 + r;
                a[m] = *(const bf16x8*)&S[row * 64 + ((cs ^ (row & 7)) << 3)];
            }
            bf16x8 b[3][2];
#pragma unroll
            for (int g = 0; g < 3; ++g)
#pragma unroll
                for (int n = 0; n < 2; ++n) {
                    int brow = 64 + g * 128 + wc + n * 16 + r;
                    b[g][n] = *(const bf16x8*)&S[brow * 64 + ((cs ^ (brow & 7)) << 3)];
                }
#pragma unroll
            for (int m = 0; m < 2; ++m)
#pragma unroll
                for (int g = 0; g < 3; ++g)
#pragma unroll
                    for (int n = 0; n < 2; ++n)
                        acc[m][g][n] = __builtin_amdgcn_mfma_f32_16x16x32_bf16(a[m], b[g][n], acc[m][g][n], 0, 0, 0);
        }
        __syncthreads();
    }

    // epilogue: x = relu(G0 + amp*G1 + att*G2 + bias) -> xs (LDS, swizzled)
#pragma unroll
    for (int m = 0; m < 2; ++m)
#pragma unroll
        for (int j = 0; j < 4; ++j) {
            int lrow = wr + m * 16 + s * 4 + j;
            int grow = row0 + lrow;
            float av = amp[grow], tv = att[grow];
#pragma unroll
            for (int n = 0; n < 2; ++n) {
                int col = wc + n * 16 + r;
                float v = acc[m][0][n][j] + av * acc[m][1][n][j] + tv * acc[m][2][n][j] + bias[col];
                v = fmaxf(v, 0.f);
                int cs2 = col >> 3;
                S[lrow * 128 + ((cs2 ^ (lrow & 7)) << 3) + (col & 7)] = (short)f2bf(v);
            }
        }
    __syncthreads();

    // issue Wp stage (k0=0) early, then copy xs -> xbuf & cat[:,0:128]
    if (PRE) {
#pragma unroll
        for (int p = 0; p < 4; ++p) {
            int lid = tid + 512 * p;
            int rr = lid >> 3, sl = lid & 7;
            gload16(Wp + (size_t)rr * 128 + ((sl ^ (rr & 7)) << 3),
                    S + 8192 + (size_t)lid * 8);
        }
    }
#pragma unroll
    for (int t = 0; t < 2; ++t) {
        int slotid = tid * 2 + t;            // 0..1023
        int rrow = slotid >> 4, cs = slotid & 15;
        bf16x8 v = *(const bf16x8*)&S[rrow * 128 + ((cs ^ (rrow & 7)) << 3)];
        int gr = row0 + rrow;
        *(bf16x8*)&xout[(size_t)gr * 128 + cs * 8] = v;
        *(bf16x8*)&catout[(size_t)gr * 768 + cs * 8] = v;
    }

    if (PRE) {
        int wr2 = (w >> 2) * 32, wc2 = (w & 3) * 64;
        f32x4 acc2[2][4];
#pragma unroll
        for (int m = 0; m < 2; ++m)
#pragma unroll
            for (int n = 0; n < 4; ++n) acc2[m][n] = (f32x4){0.f, 0.f, 0.f, 0.f};

        for (int k0 = 0; k0 < 128; k0 += 64) {
            if (k0 > 0) {
                __syncthreads();
#pragma unroll
                for (int p = 0; p < 4; ++p) {
                    int lid = tid + 512 * p;
                    int rr = lid >> 3, sl = lid & 7;
                    gload16(Wp + (size_t)rr * 128 + k0 + ((sl ^ (rr & 7)) << 3),
                            S + 8192 + (size_t)lid * 8);
                }
            }
            __syncthreads();
#pragma unroll
            for (int kk = 0; kk < 2; ++kk) {
                int csA = (k0 >> 3) + kk * 4 + s;
                int slB = kk * 4 + s;
                bf16x8 a[2];
#pragma unroll
                for (int m = 0; m < 2; ++m) {
                    int row = wr2 + m * 16 + r;
                    a[m] = *(const bf16x8*)&S[row * 128 + ((csA ^ (row & 7)) << 3)];
                }
                bf16x8 b[4];
#pragma unroll
                for (int n = 0; n < 4; ++n) {
                    int c = wc2 + n * 16 + r;
                    b[n] = *(const bf16x8*)&S[8192 + c * 64 + ((slB ^ (c & 7)) << 3)];
                }
#pragma unroll
                for (int m = 0; m < 2; ++m)
#pragma unroll
                    for (int n = 0; n < 4; ++n)
                        acc2[m][n] = __builtin_amdgcn_mfma_f32_16x16x32_bf16(a[m], b[n], acc2[m][n], 0, 0, 0);
            }
        }
#pragma unroll
        for (int m = 0; m < 2; ++m)
#pragma unroll
            for (int n = 0; n < 4; ++n) {
                int gcol = wc2 + n * 16 + r;
                float bs = bias2[gcol];
#pragma unroll
                for (int j = 0; j < 4; ++j) {
                    int grow = row0 + wr2 + m * 16 + s * 4 + j;
                    preout[(size_t)grow * 256 + gcol] = f2bf(acc2[m][n][j] + bs);
                }
            }
    }
}

// ---------------- final output ----------------

__global__ void out_kernel(const u16* __restrict__ x, const float* __restrict__ Wout,
                           const float* __restrict__ bout, float* __restrict__ y) {
    int gid = blockIdx.x * blockDim.x + threadIdx.x;
    int wid = gid >> 6, lane = threadIdx.x & 63;
    if (wid >= NN) return;
    u32 u = *(const u32*)&x[(size_t)wid * F + 2 * lane];
    float v = bflo(u) * Wout[2 * lane] + bfhi(u) * Wout[2 * lane + 1];
#pragma unroll
    for (int o = 32; o > 0; o >>= 1) v += __shfl_down(v, o, 64);
    if (lane == 0) y[wid] = v + bout[0];
}

// ---------------- host ----------------

extern "C" void kernel_launch(void* const* d_in, const int* in_sizes, int n_in,
                              void* d_out, int out_size, void* d_ws, size_t ws_size,
                              hipStream_t stream) {
    const float* x_in   = (const float*)d_in[0];
    const int*   ei     = (const int*)d_in[1];
    const float* W_pre  = (const float*)d_in[2];
    const float* b_pre  = (const float*)d_in[3];
    const float* W_post = (const float*)d_in[4];
    const float* b_post = (const float*)d_in[5];
    const float* W_lin  = (const float*)d_in[6];
    const float* b_lin  = (const float*)d_in[7];
    const float* W_out  = (const float*)d_in[8];
    const float* b_out  = (const float*)d_in[9];

    const int* src = ei;
    const int* dst = ei + NE;

    double sl = 0.0;
    for (int i = 0; i < 33; ++i) sl += log((double)(i + 1));
    float avg_log = (float)(sl / 33.0);

    char* ws = (char*)d_ws;
    size_t p = 0;
    auto alloc = [&](size_t bytes) { void* r = ws + p; p += (bytes + 255) & ~(size_t)255; return r; };
    u16*   cat     = (u16*)alloc((size_t)MPAD * CATW * 2);
    u16*   xbuf    = (u16*)alloc((size_t)MPAD * F * 2);
    u16*   preout  = (u16*)alloc((size_t)MPAD * 256 * 2);
    u16*   WpreT   = (u16*)alloc((size_t)3 * 256 * 128 * 2);
    u16*   Wpostb  = (u16*)alloc((size_t)3 * 2048 * 128 * 2);
    u16*   WlinT   = (u16*)alloc((size_t)3 * 128 * 128 * 2);
    u16*   Btcomb  = (u16*)alloc((size_t)3 * 128 * 2048 * 2);
    u16*   BtK     = (u16*)alloc((size_t)3 * 384 * 768 * 2);
    float* biaspre = (float*)alloc((size_t)3 * 256 * 4);
    float* bcomb   = (float*)alloc((size_t)3 * 128 * 4);
    float* amp     = (float*)alloc((size_t)MPAD * 4);
    float* att     = (float*)alloc((size_t)MPAD * 4);
    int*   cnt     = (int*)alloc((size_t)NN * 4);
    int*   offs    = (int*)alloc((size_t)(NN + 1) * 4);
    int*   cur     = (int*)alloc((size_t)NN * 4);
    int*   csr     = (int*)alloc((size_t)NE * 4);
    (void)ws_size;

    prep_all<<<(int)((P5 + 255) / 256), 256, 0, stream>>>(
        x_in, W_pre, W_lin, W_post, b_pre, b_post, b_lin,
        xbuf, cat, WpreT, WlinT, Wpostb, biaspre, bcomb);

    zero_ints_kernel<<<(NN + 255) / 256, 256, 0, stream>>>(cnt, cur, NN);
    hist_kernel<<<(NE + 255) / 256, 256, 0, stream>>>(dst, cnt, NE);
    scan_kernel<<<1, 1024, 0, stream>>>(cnt, offs, amp, att, avg_log, NN);
    scatter_kernel<<<(NE + 255) / 256, 256, 0, stream>>>(src, dst, offs, cur, csr, NE);

    // Btcomb[l] = (W_post@W_lin)^T  [128 x 2048], all 3 layers in one launch
    mfma_gemm<false><<<dim3(2, 16, 3), 256, 0, stream>>>(
        WlinT, 128, Wpostb, 128, nullptr, Btcomb, 2048, 128,
        16384, 262144, 262144);
    brepack_kernel<<<dim3(1152, 3), 256, 0, stream>>>(Btcomb, BtK);

    // layer-0 pre: preout = x @ [Wtop|Wbot] + [b_pre|0]
    mfma_gemm<true><<<dim3(313, 2, 1), 256, 0, stream>>>(
        xbuf, F, WpreT, 128, biaspre, preout, 256, MPAD, 0, 0, 0);

    for (int l = 0; l < NLAYER; ++l) {
        agg_kernel<<<5000, 256, 0, stream>>>(preout, offs, csr, cat);
        if (l < NLAYER - 1) {
            fused_comb<true><<<313, 512, 0, stream>>>(
                cat, BtK + (size_t)l * 294912, bcomb + (size_t)l * 128, amp, att,
                WpreT + (size_t)(l + 1) * 32768, biaspre + (size_t)(l + 1) * 256,
                xbuf, cat, preout);
        } else {
            fused_comb<false><<<313, 512, 0, stream>>>(
                cat, BtK + (size_t)l * 294912, bcomb + (size_t)l * 128, amp, att,
                nullptr, nullptr, xbuf, cat, preout);
        }
    }

    out_kernel<<<5000, 256, 0, stream>>>(xbuf, W_out, b_out, (float*)d_out);
}

// Round 5
// 264.890 us; speedup vs baseline: 1.0542x; 1.0542x over previous
//
#include <hip/hip_runtime.h>
#include <math.h>

#define NN 20000
#define NE 320000
#define F 128
#define NLAYER 3
#define MPAD 20032          // 313 * 64
#define CATW 768            // [x | mean sum std min max]
#define SCAN_NB 79          // ceil(NN/256)

typedef unsigned int u32;
typedef unsigned short u16;
typedef __attribute__((ext_vector_type(8))) short bf16x8;
typedef __attribute__((ext_vector_type(4))) float f32x4;

__device__ __forceinline__ u16 f2bf(float f) {
    union { float f; u32 u; } x{f};
    u32 r = x.u + 0x7FFFu + ((x.u >> 16) & 1u);
    return (u16)(r >> 16);
}
__device__ __forceinline__ float bflo(u32 u) { return __uint_as_float(u << 16); }
__device__ __forceinline__ float bfhi(u32 u) { return __uint_as_float(u & 0xFFFF0000u); }

__device__ __forceinline__ void gload16(const u16* g, u16* l) {
    __builtin_amdgcn_global_load_lds(
        (const __attribute__((address_space(1))) void*)g,
        (__attribute__((address_space(3))) void*)l, 16, 0, 0);
}

// ---------------- graph-structure kernels ----------------

__global__ void zero_ints_kernel(int* __restrict__ a, int* __restrict__ b, int n) {
    int i = blockIdx.x * blockDim.x + threadIdx.x;
    if (i < n) { a[i] = 0; b[i] = 0; }
}

__global__ void hist_kernel(const int* __restrict__ dst, int* __restrict__ cnt, int e) {
    int i = blockIdx.x * blockDim.x + threadIdx.x;
    if (i < e) atomicAdd(&cnt[dst[i]], 1);
}

// phase 1: per-block sums of cnt
__global__ void scan_p1(const int* __restrict__ cnt, int* __restrict__ bsum) {
    __shared__ int sh[256];
    int i = blockIdx.x * 256 + threadIdx.x;
    int t = threadIdx.x;
    sh[t] = (i < NN) ? cnt[i] : 0;
    __syncthreads();
#pragma unroll
    for (int d = 128; d > 0; d >>= 1) {
        if (t < d) sh[t] += sh[t + d];
        __syncthreads();
    }
    if (t == 0) bsum[blockIdx.x] = sh[0];
}

// phase 2: exclusive scan of block sums (single tiny block)
__global__ void scan_p2(int* __restrict__ bsum) {
    __shared__ int sh[128];
    int t = threadIdx.x;
    int v = (t < SCAN_NB) ? bsum[t] : 0;
    sh[t] = v;
    __syncthreads();
#pragma unroll
    for (int d = 1; d < 128; d <<= 1) {
        int x = (t >= d) ? sh[t - d] : 0;
        __syncthreads();
        sh[t] += x;
        __syncthreads();
    }
    if (t < SCAN_NB) bsum[t] = sh[t] - v;   // exclusive
}

// phase 3: local scan + base, write offsets and degree scalers
__global__ void scan_p3(const int* __restrict__ cnt, const int* __restrict__ bsum,
                        int* __restrict__ off, float* __restrict__ amp,
                        float* __restrict__ att, float avg_log) {
    __shared__ int sh[256];
    int i = blockIdx.x * 256 + threadIdx.x;
    int t = threadIdx.x;
    int v = (i < NN) ? cnt[i] : 0;
    sh[t] = v;
    __syncthreads();
#pragma unroll
    for (int d = 1; d < 256; d <<= 1) {
        int x = (t >= d) ? sh[t - d] : 0;
        __syncthreads();
        sh[t] += x;
        __syncthreads();
    }
    if (i < NN) {
        int incl = sh[t] + bsum[blockIdx.x];
        off[i] = incl - v;
        if (i == NN - 1) off[NN] = incl;
        float deg = fmaxf((float)v, 1.0f);
        float ld = logf(deg + 1.0f);
        amp[i] = ld / avg_log;
        att[i] = avg_log / ld;
    }
}

__global__ void scatter_kernel(const int* __restrict__ src, const int* __restrict__ dst,
                               const int* __restrict__ off, int* __restrict__ cur,
                               int* __restrict__ csr, int e) {
    int i = blockIdx.x * blockDim.x + threadIdx.x;
    if (i < e) {
        int d = dst[i];
        int p = atomicAdd(&cur[d], 1);
        csr[off[d] + p] = src[i];
    }
}

// ---------------- combined prep: converts + biases, flat-indexed ----------------

#define P0 2560000L                 // xprep NN*F
#define P1 (P0 + 3L * 256 * 128)    // wpreT
#define P2 (P1 + 3L * 128 * 128)    // wlinT
#define P3 (P2 + 3L * 2048 * 128)   // wpost
#define P4 (P3 + 3L * 256)          // biaspre
#define P5 (P4 + 3L * 128)          // bcomb

__global__ void prep_all(const float* __restrict__ x, const float* __restrict__ W_pre,
                         const float* __restrict__ W_lin, const float* __restrict__ W_post,
                         const float* __restrict__ b_pre, const float* __restrict__ b_post,
                         const float* __restrict__ b_lin,
                         u16* __restrict__ xbuf, u16* __restrict__ cat,
                         u16* __restrict__ WpreT, u16* __restrict__ WlinT,
                         u16* __restrict__ Wpostb, float* __restrict__ biaspre,
                         float* __restrict__ bcomb) {
    long i = (long)blockIdx.x * 256 + threadIdx.x;
    if (i < P0) {
        u16 h = f2bf(x[i]);
        xbuf[i] = h;
        cat[(size_t)(i >> 7) * CATW + (i & 127)] = h;
    } else if (i < P1) {
        long j = i - P0;
        int l = j / 32768, t = j % 32768;
        int c = t >> 7, k = t & 127;
        int si = (c < 128) ? (k * 128 + c) : ((k + 128) * 128 + (c - 128));
        WpreT[l * 32768 + t] = f2bf(W_pre[l * 32768 + si]);
    } else if (i < P2) {
        long j = i - P1;
        int l = j / 16384, t = j % 16384;
        int c = t >> 7, k = t & 127;
        WlinT[l * 16384 + t] = f2bf(W_lin[l * 16384 + k * 128 + c]);
    } else if (i < P3) {
        long j = i - P2;
        Wpostb[j] = f2bf(W_post[j]);
    } else if (i < P4) {
        long j = i - P3;
        int l = j / 256, t = j % 256;
        biaspre[l * 256 + t] = (t < 128) ? b_pre[l * 128 + t] : 0.f;
    } else if (i < P5) {
        long j = i - P4;
        int l = j / 128, t = j % 128;
        float s = b_lin[l * 128 + t];
        for (int c = 0; c < 128; ++c) s += b_post[l * 128 + c] * W_lin[l * 16384 + c * 128 + t];
        bcomb[l * 128 + t] = s;
    }
}

// BtK[l][row=g*128+j][k 768]
__global__ void brepack_kernel(const u16* __restrict__ Btcomb, u16* __restrict__ out) {
    int l = blockIdx.y;
    int i = blockIdx.x * 256 + threadIdx.x;   // 384*768
    if (i >= 384 * 768) return;
    int rho = i / 768, k = i % 768;
    int g = rho >> 7, j = rho & 127;
    const u16* B = Btcomb + (size_t)l * 262144;
    u16 v;
    if (k < 128) v = (g == 0) ? B[j * 2048 + k] : (u16)0;
    else         v = B[j * 2048 + 128 + g * 640 + (k - 128)];
    out[(size_t)l * 294912 + i] = v;
}

// ---------------- aggregation: one block (4 waves) per node ----------------

#define PROC(u) { float v_; \
    v_ = bflo(u); s0 += v_; q0 = fmaf(v_, v_, q0); mn0 = fminf(mn0, v_); mx0 = fmaxf(mx0, v_); \
    v_ = bfhi(u); s1 += v_; q1 = fmaf(v_, v_, q1); mn1 = fminf(mn1, v_); mx1 = fmaxf(mx1, v_); }

__global__ __launch_bounds__(256) void agg_kernel(
    const u16* __restrict__ preout, const int* __restrict__ off,
    const int* __restrict__ csr, u16* __restrict__ cat) {
    int node = blockIdx.x;
    int tid = threadIdx.x, w = tid >> 6, lane = tid & 63;
    int o0 = off[node], o1 = off[node + 1];
    const u32* bpl = (const u32*)preout + 64 + lane;   // row stride 128 u32
    float s0 = 0, s1 = 0, q0 = 0, q1 = 0;
    float mn0 = 1e30f, mn1 = 1e30f, mx0 = -1e30f, mx1 = -1e30f;
    int j = o0 + w;
    for (; j + 4 < o1; j += 8) {             // two stride-4 steps, loads paired
        int i0 = csr[j], i1 = csr[j + 4];
        u32 u0 = bpl[(size_t)i0 * 128];
        u32 u1 = bpl[(size_t)i1 * 128];
        PROC(u0); PROC(u1);
    }
    if (j < o1) { u32 u = bpl[(size_t)csr[j] * 128]; PROC(u); }

    __shared__ float red[8][256];
    red[0][tid] = s0; red[1][tid] = s1; red[2][tid] = q0; red[3][tid] = q1;
    red[4][tid] = mn0; red[5][tid] = mn1; red[6][tid] = mx0; red[7][tid] = mx1;
    __syncthreads();
    if (w != 0) return;

    s0 = 0; s1 = 0; q0 = 0; q1 = 0;
    mn0 = 1e30f; mn1 = 1e30f; mx0 = -1e30f; mx1 = -1e30f;
#pragma unroll
    for (int ww = 0; ww < 4; ++ww) {
        int sl = ww * 64 + lane;
        s0 += red[0][sl]; s1 += red[1][sl];
        q0 += red[2][sl]; q1 += red[3][sl];
        mn0 = fminf(mn0, red[4][sl]); mn1 = fminf(mn1, red[5][sl]);
        mx0 = fmaxf(mx0, red[6][sl]); mx1 = fmaxf(mx1, red[7][sl]);
    }

    int degi = o1 - o0;
    float mean0, mean1, sum0, sum1, std0, std1, lo0, lo1, hi0, hi1;
    if (degi == 0) {
        sum0 = sum1 = 0.f; mean0 = mean1 = 0.f;
        std0 = std1 = sqrtf(1e-5f);
        lo0 = lo1 = hi0 = hi1 = 0.f;
    } else {
        u32 uc = ((const u32*)preout)[(size_t)node * 128 + lane];
        float c0 = bflo(uc), c1 = bfhi(uc), dg = (float)degi;
        sum0 = dg * c0 + s0; mean0 = sum0 / dg;
        sum1 = dg * c1 + s1; mean1 = sum1 / dg;
        float msq0 = c0 * c0 + (2.f * c0 * s0 + q0) / dg;
        float msq1 = c1 * c1 + (2.f * c1 * s1 + q1) / dg;
        std0 = sqrtf(fmaxf(msq0 - mean0 * mean0, 0.f) + 1e-5f);
        std1 = sqrtf(fmaxf(msq1 - mean1 * mean1, 0.f) + 1e-5f);
        lo0 = c0 + mn0; lo1 = c1 + mn1; hi0 = c0 + mx0; hi1 = c1 + mx1;
    }
    u32* cr = (u32*)cat + (size_t)node * (CATW / 2) + 64 + lane;
    float f0[5] = {mean0, sum0, std0, lo0, hi0};
    float f1[5] = {mean1, sum1, std1, lo1, hi1};
#pragma unroll
    for (int a = 0; a < 5; ++a)
        cr[a * 64] = (u32)f2bf(f0[a]) | ((u32)f2bf(f1[a]) << 16);
}

// ---------------- generic bf16 MFMA GEMM (layer-0 pre + weight-product) ----------------

template <bool BIAS>
__global__ __launch_bounds__(256) void mfma_gemm(
    const u16* __restrict__ A, int lda,
    const u16* __restrict__ Bt, int K,
    const float* __restrict__ bias,
    u16* __restrict__ C, int ldc, int Mreal,
    size_t aS, size_t bS, size_t cS) {
    __shared__ u16 As[64 * 32];
    __shared__ u16 Bs[128 * 32];
    int z = blockIdx.z;
    A += (size_t)z * aS; Bt += (size_t)z * bS; C += (size_t)z * cS;
    int tid = threadIdx.x;
    int w = tid >> 6, lane = tid & 63;
    int row0 = blockIdx.x * 64, col0 = blockIdx.y * 128;

    int arow = tid >> 2, asl = tid & 3;
    const u16* agp = A + (size_t)(row0 + arow) * lda + ((asl ^ ((arow >> 1) & 3)) << 3);
    u16* alds = As + w * 512;
    int br0 = tid >> 2;
    int br1 = 64 + (tid >> 2);
    const u16* bgp0 = Bt + (size_t)(col0 + br0) * K + (((tid & 3) ^ ((br0 >> 1) & 3)) << 3);
    const u16* bgp1 = Bt + (size_t)(col0 + br1) * K + (((tid & 3) ^ ((br1 >> 1) & 3)) << 3);
    u16* blds0 = Bs + w * 512;
    u16* blds1 = Bs + 2048 + w * 512;

    f32x4 acc[2][4];
#pragma unroll
    for (int m = 0; m < 2; ++m)
#pragma unroll
        for (int n = 0; n < 4; ++n) acc[m][n] = (f32x4){0.f, 0.f, 0.f, 0.f};

    int s = lane >> 4, r = lane & 15;
    int wr = (w >> 1) * 32, wc = (w & 1) * 64;

    for (int k0 = 0; k0 < K; k0 += 32) {
        gload16(agp + k0, alds);
        gload16(bgp0 + k0, blds0);
        gload16(bgp1 + k0, blds1);
        __syncthreads();
        bf16x8 a[2], b[4];
#pragma unroll
        for (int m = 0; m < 2; ++m) {
            int row = wr + m * 16 + r;
            a[m] = *(const bf16x8*)&As[row * 32 + ((s ^ ((row >> 1) & 3)) << 3)];
        }
#pragma unroll
        for (int n = 0; n < 4; ++n) {
            int col = wc + n * 16 + r;
            b[n] = *(const bf16x8*)&Bs[col * 32 + ((s ^ ((col >> 1) & 3)) << 3)];
        }
#pragma unroll
        for (int m = 0; m < 2; ++m)
#pragma unroll
            for (int n = 0; n < 4; ++n)
                acc[m][n] = __builtin_amdgcn_mfma_f32_16x16x32_bf16(a[m], b[n], acc[m][n], 0, 0, 0);
        __syncthreads();
    }

#pragma unroll
    for (int m = 0; m < 2; ++m) {
#pragma unroll
        for (int n = 0; n < 4; ++n) {
            int gcol = col0 + wc + n * 16 + r;
            float bs = BIAS ? bias[gcol] : 0.f;
#pragma unroll
            for (int j = 0; j < 4; ++j) {
                int grow = row0 + wr + m * 16 + s * 4 + j;
                if (grow < Mreal)
                    C[(size_t)grow * ldc + gcol] = f2bf(acc[m][n][j] + bs);
            }
        }
    }
}

// ---------------- fused comb GEMM (+ optional pre_nn for next layer) ----------------

template <bool PRE>
__global__ __launch_bounds__(512) void fused_comb(
    const u16* __restrict__ A,          // cat [MPAD][768]
    const u16* __restrict__ BtK,        // [384][768]
    const float* __restrict__ bias,     // bcomb 128
    const float* __restrict__ amp, const float* __restrict__ att,   // MPAD
    const u16* __restrict__ Wp,         // WpreT next layer [256][128]
    const float* __restrict__ bias2,    // biaspre next layer [256]
    u16* __restrict__ xout,             // xbuf [MPAD][128]
    u16* __restrict__ catout,           // cat cols 0..127
    u16* __restrict__ preout) {         // [MPAD][256]
    __shared__ u16 S[448 * 64];         // 56 KB
    int tid = threadIdx.x;
    int row0 = blockIdx.x * 64;
    int w = tid >> 6, lane = tid & 63;
    int r = lane & 15, s = lane >> 4;
    int wr = (w >> 2) * 32, wc = (w & 3) * 32;

    const u16* gp[7];
#pragma unroll
    for (int p = 0; p < 7; ++p) {
        int lid = tid + 512 * p;
        int row = lid >> 3, sl = lid & 7;
        int koff = (sl ^ (row & 7)) << 3;
        gp[p] = (row < 64) ? A + (size_t)(row0 + row) * 768 + koff
                           : BtK + (size_t)(row - 64) * 768 + koff;
    }

    f32x4 acc[2][3][2];
#pragma unroll
    for (int m = 0; m < 2; ++m)
#pragma unroll
        for (int g = 0; g < 3; ++g)
#pragma unroll
            for (int n = 0; n < 2; ++n) acc[m][g][n] = (f32x4){0.f, 0.f, 0.f, 0.f};

    for (int k0 = 0; k0 < 768; k0 += 64) {
#pragma unroll
        for (int p = 0; p < 7; ++p)
            gload16(gp[p] + k0, S + (size_t)(tid + 512 * p) * 8);
        __syncthreads();
#pragma unroll
        for (int kk = 0; kk < 2; ++kk) {
            int cs = kk * 4 + s;
            bf16x8 a[2];
#pragma unroll
            for (int m = 0; m < 2; ++m) {
                int row = wr + m * 16 + r;
                a[m] = *(const bf16x8*)&S[row * 64 + ((cs ^ (row & 7)) << 3)];
            }
            bf16x8 b[3][2];
#pragma unroll
            for (int g = 0; g < 3; ++g)
#pragma unroll
                for (int n = 0; n < 2; ++n) {
                    int brow = 64 + g * 128 + wc + n * 16 + r;
                    b[g][n] = *(const bf16x8*)&S[brow * 64 + ((cs ^ (brow & 7)) << 3)];
                }
#pragma unroll
            for (int m = 0; m < 2; ++m)
#pragma unroll
                for (int g = 0; g < 3; ++g)
#pragma unroll
                    for (int n = 0; n < 2; ++n)
                        acc[m][g][n] = __builtin_amdgcn_mfma_f32_16x16x32_bf16(a[m], b[g][n], acc[m][g][n], 0, 0, 0);
        }
        __syncthreads();
    }

    // epilogue: x = relu(G0 + amp*G1 + att*G2 + bias) -> LDS (swizzled)
#pragma unroll
    for (int m = 0; m < 2; ++m)
#pragma unroll
        for (int j = 0; j < 4; ++j) {
            int lrow = wr + m * 16 + s * 4 + j;
            int grow = row0 + lrow;
            float av = amp[grow], tv = att[grow];
#pragma unroll
            for (int n = 0; n < 2; ++n) {
                int col = wc + n * 16 + r;
                float v = acc[m][0][n][j] + av * acc[m][1][n][j] + tv * acc[m][2][n][j] + bias[col];
                v = fmaxf(v, 0.f);
                int cs2 = col >> 3;
                S[lrow * 128 + ((cs2 ^ (lrow & 7)) << 3) + (col & 7)] = (short)f2bf(v);
            }
        }
    __syncthreads();

    if (PRE) {
#pragma unroll
        for (int p = 0; p < 4; ++p) {
            int lid = tid + 512 * p;
            int rr = lid >> 3, sl = lid & 7;
            gload16(Wp + (size_t)rr * 128 + ((sl ^ (rr & 7)) << 3),
                    S + 8192 + (size_t)lid * 8);
        }
    }
#pragma unroll
    for (int t = 0; t < 2; ++t) {
        int slotid = tid * 2 + t;            // 0..1023
        int rrow = slotid >> 4, cs = slotid & 15;
        bf16x8 v = *(const bf16x8*)&S[rrow * 128 + ((cs ^ (rrow & 7)) << 3)];
        int gr = row0 + rrow;
        *(bf16x8*)&xout[(size_t)gr * 128 + cs * 8] = v;
        *(bf16x8*)&catout[(size_t)gr * 768 + cs * 8] = v;
    }

    if (PRE) {
        int wr2 = (w >> 2) * 32, wc2 = (w & 3) * 64;
        f32x4 acc2[2][4];
#pragma unroll
        for (int m = 0; m < 2; ++m)
#pragma unroll
            for (int n = 0; n < 4; ++n) acc2[m][n] = (f32x4){0.f, 0.f, 0.f, 0.f};

        for (int k0 = 0; k0 < 128; k0 += 64) {
            if (k0 > 0) {
                __syncthreads();
#pragma unroll
                for (int p = 0; p < 4; ++p) {
                    int lid = tid + 512 * p;
                    int rr = lid >> 3, sl = lid & 7;
                    gload16(Wp + (size_t)rr * 128 + k0 + ((sl ^ (rr & 7)) << 3),
                            S + 8192 + (size_t)lid * 8);
                }
            }
            __syncthreads();
#pragma unroll
            for (int kk = 0; kk < 2; ++kk) {
                int csA = (k0 >> 3) + kk * 4 + s;
                int slB = kk * 4 + s;
                bf16x8 a[2];
#pragma unroll
                for (int m = 0; m < 2; ++m) {
                    int row = wr2 + m * 16 + r;
                    a[m] = *(const bf16x8*)&S[row * 128 + ((csA ^ (row & 7)) << 3)];
                }
                bf16x8 b[4];
#pragma unroll
                for (int n = 0; n < 4; ++n) {
                    int c = wc2 + n * 16 + r;
                    b[n] = *(const bf16x8*)&S[8192 + c * 64 + ((slB ^ (c & 7)) << 3)];
                }
#pragma unroll
                for (int m = 0; m < 2; ++m)
#pragma unroll
                    for (int n = 0; n < 4; ++n)
                        acc2[m][n] = __builtin_amdgcn_mfma_f32_16x16x32_bf16(a[m], b[n], acc2[m][n], 0, 0, 0);
            }
        }
#pragma unroll
        for (int m = 0; m < 2; ++m)
#pragma unroll
            for (int n = 0; n < 4; ++n) {
                int gcol = wc2 + n * 16 + r;
                float bs = bias2[gcol];
#pragma unroll
                for (int j = 0; j < 4; ++j) {
                    int grow = row0 + wr2 + m * 16 + s * 4 + j;
                    preout[(size_t)grow * 256 + gcol] = f2bf(acc2[m][n][j] + bs);
                }
            }
    }
}

// ---------------- final output ----------------

__global__ void out_kernel(const u16* __restrict__ x, const float* __restrict__ Wout,
                           const float* __restrict__ bout, float* __restrict__ y) {
    int gid = blockIdx.x * blockDim.x + threadIdx.x;
    int wid = gid >> 6, lane = threadIdx.x & 63;
    if (wid >= NN) return;
    u32 u = *(const u32*)&x[(size_t)wid * F + 2 * lane];
    float v = bflo(u) * Wout[2 * lane] + bfhi(u) * Wout[2 * lane + 1];
#pragma unroll
    for (int o = 32; o > 0; o >>= 1) v += __shfl_down(v, o, 64);
    if (lane == 0) y[wid] = v + bout[0];
}

// ---------------- host ----------------

extern "C" void kernel_launch(void* const* d_in, const int* in_sizes, int n_in,
                              void* d_out, int out_size, void* d_ws, size_t ws_size,
                              hipStream_t stream) {
    const float* x_in   = (const float*)d_in[0];
    const int*   ei     = (const int*)d_in[1];
    const float* W_pre  = (const float*)d_in[2];
    const float* b_pre  = (const float*)d_in[3];
    const float* W_post = (const float*)d_in[4];
    const float* b_post = (const float*)d_in[5];
    const float* W_lin  = (const float*)d_in[6];
    const float* b_lin  = (const float*)d_in[7];
    const float* W_out  = (const float*)d_in[8];
    const float* b_out  = (const float*)d_in[9];

    const int* src = ei;
    const int* dst = ei + NE;

    double sl = 0.0;
    for (int i = 0; i < 33; ++i) sl += log((double)(i + 1));
    float avg_log = (float)(sl / 33.0);

    char* ws = (char*)d_ws;
    size_t p = 0;
    auto alloc = [&](size_t bytes) { void* r = ws + p; p += (bytes + 255) & ~(size_t)255; return r; };
    u16*   cat     = (u16*)alloc((size_t)MPAD * CATW * 2);
    u16*   xbuf    = (u16*)alloc((size_t)MPAD * F * 2);
    u16*   preout  = (u16*)alloc((size_t)MPAD * 256 * 2);
    u16*   WpreT   = (u16*)alloc((size_t)3 * 256 * 128 * 2);
    u16*   Wpostb  = (u16*)alloc((size_t)3 * 2048 * 128 * 2);
    u16*   WlinT   = (u16*)alloc((size_t)3 * 128 * 128 * 2);
    u16*   Btcomb  = (u16*)alloc((size_t)3 * 128 * 2048 * 2);
    u16*   BtK     = (u16*)alloc((size_t)3 * 384 * 768 * 2);
    float* biaspre = (float*)alloc((size_t)3 * 256 * 4);
    float* bcomb   = (float*)alloc((size_t)3 * 128 * 4);
    float* amp     = (float*)alloc((size_t)MPAD * 4);
    float* att     = (float*)alloc((size_t)MPAD * 4);
    int*   cnt     = (int*)alloc((size_t)NN * 4);
    int*   offs    = (int*)alloc((size_t)(NN + 1) * 4);
    int*   cur     = (int*)alloc((size_t)NN * 4);
    int*   csr     = (int*)alloc((size_t)NE * 4);
    int*   bsum    = (int*)alloc((size_t)SCAN_NB * 4);
    (void)ws_size;

    prep_all<<<(int)((P5 + 255) / 256), 256, 0, stream>>>(
        x_in, W_pre, W_lin, W_post, b_pre, b_post, b_lin,
        xbuf, cat, WpreT, WlinT, Wpostb, biaspre, bcomb);

    zero_ints_kernel<<<(NN + 255) / 256, 256, 0, stream>>>(cnt, cur, NN);
    hist_kernel<<<(NE + 255) / 256, 256, 0, stream>>>(dst, cnt, NE);
    scan_p1<<<SCAN_NB, 256, 0, stream>>>(cnt, bsum);
    scan_p2<<<1, 128, 0, stream>>>(bsum);
    scan_p3<<<SCAN_NB, 256, 0, stream>>>(cnt, bsum, offs, amp, att, avg_log);
    scatter_kernel<<<(NE + 255) / 256, 256, 0, stream>>>(src, dst, offs, cur, csr, NE);

    // Btcomb[l] = (W_post@W_lin)^T  [128 x 2048], all 3 layers in one launch
    mfma_gemm<false><<<dim3(2, 16, 3), 256, 0, stream>>>(
        WlinT, 128, Wpostb, 128, nullptr, Btcomb, 2048, 128,
        16384, 262144, 262144);
    brepack_kernel<<<dim3(1152, 3), 256, 0, stream>>>(Btcomb, BtK);

    // layer-0 pre: preout = x @ [Wtop|Wbot] + [b_pre|0]
    mfma_gemm<true><<<dim3(313, 2, 1), 256, 0, stream>>>(
        xbuf, F, WpreT, 128, biaspre, preout, 256, MPAD, 0, 0, 0);

    for (int l = 0; l < NLAYER; ++l) {
        agg_kernel<<<NN, 256, 0, stream>>>(preout, offs, csr, cat);
        if (l < NLAYER - 1) {
            fused_comb<true><<<313, 512, 0, stream>>>(
                cat, BtK + (size_t)l * 294912, bcomb + (size_t)l * 128, amp, att,
                WpreT + (size_t)(l + 1) * 32768, biaspre + (size_t)(l + 1) * 256,
                xbuf, cat, preout);
        } else {
            fused_comb<false><<<313, 512, 0, stream>>>(
                cat, BtK + (size_t)l * 294912, bcomb + (size_t)l * 128, amp, att,
                nullptr, nullptr, xbuf, cat, preout);
        }
    }

    out_kernel<<<5000, 256, 0, stream>>>(xbuf, W_out, b_out, (float*)d_out);
}

// Round 6
// 258.437 us; speedup vs baseline: 1.0805x; 1.0250x over previous
//
#include <hip/hip_runtime.h>
#include <math.h>

#define NN 20000
#define NE 320000
#define F 128
#define NLAYER 3
#define MPAD 20032          // 313 * 64
#define CATW 768            // [x | mean sum std min max]
#define SCAN_NB 79          // ceil(NN/256)

typedef unsigned int u32;
typedef unsigned short u16;
typedef __attribute__((ext_vector_type(8))) short bf16x8;
typedef __attribute__((ext_vector_type(4))) float f32x4;

__device__ __forceinline__ u16 f2bf(float f) {
    union { float f; u32 u; } x{f};
    u32 r = x.u + 0x7FFFu + ((x.u >> 16) & 1u);
    return (u16)(r >> 16);
}
__device__ __forceinline__ float bflo(u32 u) { return __uint_as_float(u << 16); }
__device__ __forceinline__ float bfhi(u32 u) { return __uint_as_float(u & 0xFFFF0000u); }

__device__ __forceinline__ void gload16(const u16* g, u16* l) {
    __builtin_amdgcn_global_load_lds(
        (const __attribute__((address_space(1))) void*)g,
        (__attribute__((address_space(3))) void*)l, 16, 0, 0);
}

// ---------------- graph-structure kernels ----------------

__global__ void zero_ints_kernel(int* __restrict__ a, int* __restrict__ b, int n) {
    int i = blockIdx.x * blockDim.x + threadIdx.x;
    if (i < n) { a[i] = 0; b[i] = 0; }
}

__global__ void hist_kernel(const int* __restrict__ dst, int* __restrict__ cnt, int e) {
    int i = blockIdx.x * blockDim.x + threadIdx.x;
    if (i < e) atomicAdd(&cnt[dst[i]], 1);
}

__global__ void scan_p1(const int* __restrict__ cnt, int* __restrict__ bsum) {
    __shared__ int sh[256];
    int i = blockIdx.x * 256 + threadIdx.x;
    int t = threadIdx.x;
    sh[t] = (i < NN) ? cnt[i] : 0;
    __syncthreads();
#pragma unroll
    for (int d = 128; d > 0; d >>= 1) {
        if (t < d) sh[t] += sh[t + d];
        __syncthreads();
    }
    if (t == 0) bsum[blockIdx.x] = sh[0];
}

__global__ void scan_p2(int* __restrict__ bsum) {
    __shared__ int sh[128];
    int t = threadIdx.x;
    int v = (t < SCAN_NB) ? bsum[t] : 0;
    sh[t] = v;
    __syncthreads();
#pragma unroll
    for (int d = 1; d < 128; d <<= 1) {
        int x = (t >= d) ? sh[t - d] : 0;
        __syncthreads();
        sh[t] += x;
        __syncthreads();
    }
    if (t < SCAN_NB) bsum[t] = sh[t] - v;   // exclusive
}

__global__ void scan_p3(const int* __restrict__ cnt, const int* __restrict__ bsum,
                        int* __restrict__ off, float* __restrict__ amp,
                        float* __restrict__ att, float avg_log) {
    __shared__ int sh[256];
    int i = blockIdx.x * 256 + threadIdx.x;
    int t = threadIdx.x;
    int v = (i < NN) ? cnt[i] : 0;
    sh[t] = v;
    __syncthreads();
#pragma unroll
    for (int d = 1; d < 256; d <<= 1) {
        int x = (t >= d) ? sh[t - d] : 0;
        __syncthreads();
        sh[t] += x;
        __syncthreads();
    }
    if (i < NN) {
        int incl = sh[t] + bsum[blockIdx.x];
        off[i] = incl - v;
        if (i == NN - 1) off[NN] = incl;
        float deg = fmaxf((float)v, 1.0f);
        float ld = logf(deg + 1.0f);
        amp[i] = ld / avg_log;
        att[i] = avg_log / ld;
    }
}

__global__ void scatter_kernel(const int* __restrict__ src, const int* __restrict__ dst,
                               const int* __restrict__ off, int* __restrict__ cur,
                               int* __restrict__ csr, int e) {
    int i = blockIdx.x * blockDim.x + threadIdx.x;
    if (i < e) {
        int d = dst[i];
        int p = atomicAdd(&cur[d], 1);
        csr[off[d] + p] = src[i];
    }
}

// ---------------- combined prep: converts + biases, flat-indexed ----------------

#define P0 2560000L                 // xprep NN*F
#define P1 (P0 + 3L * 256 * 128)    // wpreT
#define P2 (P1 + 3L * 128 * 128)    // wlinT
#define P3 (P2 + 3L * 2048 * 128)   // wpost
#define P4 (P3 + 3L * 256)          // biaspre
#define P5 (P4 + 3L * 128)          // bcomb

__global__ void prep_all(const float* __restrict__ x, const float* __restrict__ W_pre,
                         const float* __restrict__ W_lin, const float* __restrict__ W_post,
                         const float* __restrict__ b_pre, const float* __restrict__ b_post,
                         const float* __restrict__ b_lin,
                         u16* __restrict__ xbuf, u16* __restrict__ cat,
                         u16* __restrict__ WpreT, u16* __restrict__ WlinT,
                         u16* __restrict__ Wpostb, float* __restrict__ biaspre,
                         float* __restrict__ bcomb) {
    long i = (long)blockIdx.x * 256 + threadIdx.x;
    if (i < P0) {
        u16 h = f2bf(x[i]);
        xbuf[i] = h;
        cat[(size_t)(i >> 7) * CATW + (i & 127)] = h;
    } else if (i < P1) {
        long j = i - P0;
        int l = j / 32768, t = j % 32768;
        int c = t >> 7, k = t & 127;
        int si = (c < 128) ? (k * 128 + c) : ((k + 128) * 128 + (c - 128));
        WpreT[l * 32768 + t] = f2bf(W_pre[l * 32768 + si]);
    } else if (i < P2) {
        long j = i - P1;
        int l = j / 16384, t = j % 16384;
        int c = t >> 7, k = t & 127;
        WlinT[l * 16384 + t] = f2bf(W_lin[l * 16384 + k * 128 + c]);
    } else if (i < P3) {
        long j = i - P2;
        Wpostb[j] = f2bf(W_post[j]);
    } else if (i < P4) {
        long j = i - P3;
        int l = j / 256, t = j % 256;
        biaspre[l * 256 + t] = (t < 128) ? b_pre[l * 128 + t] : 0.f;
    } else if (i < P5) {
        long j = i - P4;
        int l = j / 128, t = j % 128;
        float s = b_lin[l * 128 + t];
        for (int c = 0; c < 128; ++c) s += b_post[l * 128 + c] * W_lin[l * 16384 + c * 128 + t];
        bcomb[l * 128 + t] = s;
    }
}

// BtK[l][row=g*128+j][k 768]
__global__ void brepack_kernel(const u16* __restrict__ Btcomb, u16* __restrict__ out) {
    int l = blockIdx.y;
    int i = blockIdx.x * 256 + threadIdx.x;   // 384*768
    if (i >= 384 * 768) return;
    int rho = i / 768, k = i % 768;
    int g = rho >> 7, j = rho & 127;
    const u16* B = Btcomb + (size_t)l * 262144;
    u16 v;
    if (k < 128) v = (g == 0) ? B[j * 2048 + k] : (u16)0;
    else         v = B[j * 2048 + 128 + g * 640 + (k - 128)];
    out[(size_t)l * 294912 + i] = v;
}

// ---------------- aggregation: one block (4 waves) per node ----------------

#define PROC(u) { float v_; \
    v_ = bflo(u); s0 += v_; q0 = fmaf(v_, v_, q0); mn0 = fminf(mn0, v_); mx0 = fmaxf(mx0, v_); \
    v_ = bfhi(u); s1 += v_; q1 = fmaf(v_, v_, q1); mn1 = fminf(mn1, v_); mx1 = fmaxf(mx1, v_); }

__global__ __launch_bounds__(256) void agg_kernel(
    const u16* __restrict__ preout, const int* __restrict__ off,
    const int* __restrict__ csr, u16* __restrict__ cat) {
    int node = blockIdx.x;
    int tid = threadIdx.x, w = tid >> 6, lane = tid & 63;
    int o0 = off[node], o1 = off[node + 1];
    const u32* bpl = (const u32*)preout + 64 + lane;   // row stride 128 u32
    float s0 = 0, s1 = 0, q0 = 0, q1 = 0;
    float mn0 = 1e30f, mn1 = 1e30f, mx0 = -1e30f, mx1 = -1e30f;
    int j = o0 + w;
    for (; j + 4 < o1; j += 8) {
        int i0 = csr[j], i1 = csr[j + 4];
        u32 u0 = bpl[(size_t)i0 * 128];
        u32 u1 = bpl[(size_t)i1 * 128];
        PROC(u0); PROC(u1);
    }
    if (j < o1) { u32 u = bpl[(size_t)csr[j] * 128]; PROC(u); }

    __shared__ float red[8][256];
    red[0][tid] = s0; red[1][tid] = s1; red[2][tid] = q0; red[3][tid] = q1;
    red[4][tid] = mn0; red[5][tid] = mn1; red[6][tid] = mx0; red[7][tid] = mx1;
    __syncthreads();
    if (w != 0) return;

    s0 = 0; s1 = 0; q0 = 0; q1 = 0;
    mn0 = 1e30f; mn1 = 1e30f; mx0 = -1e30f; mx1 = -1e30f;
#pragma unroll
    for (int ww = 0; ww < 4; ++ww) {
        int sl = ww * 64 + lane;
        s0 += red[0][sl]; s1 += red[1][sl];
        q0 += red[2][sl]; q1 += red[3][sl];
        mn0 = fminf(mn0, red[4][sl]); mn1 = fminf(mn1, red[5][sl]);
        mx0 = fmaxf(mx0, red[6][sl]); mx1 = fmaxf(mx1, red[7][sl]);
    }

    int degi = o1 - o0;
    float mean0, mean1, sum0, sum1, std0, std1, lo0, lo1, hi0, hi1;
    if (degi == 0) {
        sum0 = sum1 = 0.f; mean0 = mean1 = 0.f;
        std0 = std1 = sqrtf(1e-5f);
        lo0 = lo1 = hi0 = hi1 = 0.f;
    } else {
        u32 uc = ((const u32*)preout)[(size_t)node * 128 + lane];
        float c0 = bflo(uc), c1 = bfhi(uc), dg = (float)degi;
        sum0 = dg * c0 + s0; mean0 = sum0 / dg;
        sum1 = dg * c1 + s1; mean1 = sum1 / dg;
        float msq0 = c0 * c0 + (2.f * c0 * s0 + q0) / dg;
        float msq1 = c1 * c1 + (2.f * c1 * s1 + q1) / dg;
        std0 = sqrtf(fmaxf(msq0 - mean0 * mean0, 0.f) + 1e-5f);
        std1 = sqrtf(fmaxf(msq1 - mean1 * mean1, 0.f) + 1e-5f);
        lo0 = c0 + mn0; lo1 = c1 + mn1; hi0 = c0 + mx0; hi1 = c1 + mx1;
    }
    u32* cr = (u32*)cat + (size_t)node * (CATW / 2) + 64 + lane;
    float f0[5] = {mean0, sum0, std0, lo0, hi0};
    float f1[5] = {mean1, sum1, std1, lo1, hi1};
#pragma unroll
    for (int a = 0; a < 5; ++a)
        cr[a * 64] = (u32)f2bf(f0[a]) | ((u32)f2bf(f1[a]) << 16);
}

// ---------------- generic bf16 MFMA GEMM (pre_nn + weight-product) ----------------

template <bool BIAS>
__global__ __launch_bounds__(256) void mfma_gemm(
    const u16* __restrict__ A, int lda,
    const u16* __restrict__ Bt, int K,
    const float* __restrict__ bias,
    u16* __restrict__ C, int ldc, int Mreal,
    size_t aS, size_t bS, size_t cS) {
    __shared__ u16 As[64 * 32];
    __shared__ u16 Bs[128 * 32];
    int z = blockIdx.z;
    A += (size_t)z * aS; Bt += (size_t)z * bS; C += (size_t)z * cS;
    int tid = threadIdx.x;
    int w = tid >> 6, lane = tid & 63;
    int row0 = blockIdx.x * 64, col0 = blockIdx.y * 128;

    int arow = tid >> 2, asl = tid & 3;
    const u16* agp = A + (size_t)(row0 + arow) * lda + ((asl ^ ((arow >> 1) & 3)) << 3);
    u16* alds = As + w * 512;
    int br0 = tid >> 2;
    int br1 = 64 + (tid >> 2);
    const u16* bgp0 = Bt + (size_t)(col0 + br0) * K + (((tid & 3) ^ ((br0 >> 1) & 3)) << 3);
    const u16* bgp1 = Bt + (size_t)(col0 + br1) * K + (((tid & 3) ^ ((br1 >> 1) & 3)) << 3);
    u16* blds0 = Bs + w * 512;
    u16* blds1 = Bs + 2048 + w * 512;

    f32x4 acc[2][4];
#pragma unroll
    for (int m = 0; m < 2; ++m)
#pragma unroll
        for (int n = 0; n < 4; ++n) acc[m][n] = (f32x4){0.f, 0.f, 0.f, 0.f};

    int s = lane >> 4, r = lane & 15;
    int wr = (w >> 1) * 32, wc = (w & 1) * 64;

    for (int k0 = 0; k0 < K; k0 += 32) {
        gload16(agp + k0, alds);
        gload16(bgp0 + k0, blds0);
        gload16(bgp1 + k0, blds1);
        __syncthreads();
        bf16x8 a[2], b[4];
#pragma unroll
        for (int m = 0; m < 2; ++m) {
            int row = wr + m * 16 + r;
            a[m] = *(const bf16x8*)&As[row * 32 + ((s ^ ((row >> 1) & 3)) << 3)];
        }
#pragma unroll
        for (int n = 0; n < 4; ++n) {
            int col = wc + n * 16 + r;
            b[n] = *(const bf16x8*)&Bs[col * 32 + ((s ^ ((col >> 1) & 3)) << 3)];
        }
#pragma unroll
        for (int m = 0; m < 2; ++m)
#pragma unroll
            for (int n = 0; n < 4; ++n)
                acc[m][n] = __builtin_amdgcn_mfma_f32_16x16x32_bf16(a[m], b[n], acc[m][n], 0, 0, 0);
        __syncthreads();
    }

#pragma unroll
    for (int m = 0; m < 2; ++m) {
#pragma unroll
        for (int n = 0; n < 4; ++n) {
            int gcol = col0 + wc + n * 16 + r;
            float bs = BIAS ? bias[gcol] : 0.f;
#pragma unroll
            for (int j = 0; j < 4; ++j) {
                int grow = row0 + wr + m * 16 + s * 4 + j;
                if (grow < Mreal)
                    C[(size_t)grow * ldc + gcol] = f2bf(acc[m][n][j] + bs);
            }
        }
    }
}

// ---------------- comb2: double-buffered 2-phase comb GEMM ----------------
// grid (313, 2), 256 threads (4 waves). Tile: 64 rows x 64 out-cols x 3 groups.
// K-step 32, LDS 2 x (256 rows x 32 k) = 32 KB -> up to 5 blocks/CU.
// Schedule: STAGE(next) issued BEFORE compute(cur); one barrier per step (T3 min).

__global__ __launch_bounds__(256) void comb2(
    const u16* __restrict__ A,          // cat [MPAD][768]
    const u16* __restrict__ BtK,        // [384][768], row = g*128 + outcol
    const float* __restrict__ bias,     // bcomb 128
    const float* __restrict__ amp, const float* __restrict__ att,
    u16* __restrict__ xout,             // xbuf [MPAD][128]
    u16* __restrict__ catout) {         // cat cols 0..127
    __shared__ u16 S[2][8192];          // 2 x 16 KB
    int tid = threadIdx.x;
    int row0 = blockIdx.x * 64;
    int cb = blockIdx.y;                // 64-col half
    int w = tid >> 6, lane = tid & 63;
    int r = lane & 15, s4 = lane >> 4;
    int wr = (w >> 1) * 32, wc = (w & 1) * 32;

    // staging pointers: thread covers tile rows {tid>>2, +64, +128, +192}, slot tid&3
    const u16* gp[4];
#pragma unroll
    for (int p = 0; p < 4; ++p) {
        int lid = tid + 256 * p;
        int rt = lid >> 2, q = lid & 3;
        int koff = (q ^ ((rt >> 1) & 3)) << 3;     // pre-swizzled source
        if (rt < 64) gp[p] = A + (size_t)(row0 + rt) * 768 + koff;
        else {
            int rb = rt - 64, g = rb >> 6, jj = rb & 63;
            gp[p] = BtK + (size_t)(g * 128 + cb * 64 + jj) * 768 + koff;
        }
    }

    f32x4 acc[2][3][2];
#pragma unroll
    for (int m = 0; m < 2; ++m)
#pragma unroll
        for (int g = 0; g < 3; ++g)
#pragma unroll
            for (int n = 0; n < 2; ++n) acc[m][g][n] = (f32x4){0.f, 0.f, 0.f, 0.f};

    // prologue: stage k-tile 0 into buf 0
#pragma unroll
    for (int p = 0; p < 4; ++p)
        gload16(gp[p], &S[0][(size_t)(tid + 256 * p) * 8]);
    __syncthreads();

    int buf = 0;
    for (int t = 0; t < 23; ++t) {
        // issue next tile's loads first (stay in flight across compute)
        int k0 = (t + 1) * 32;
#pragma unroll
        for (int p = 0; p < 4; ++p)
            gload16(gp[p] + k0, &S[buf ^ 1][(size_t)(tid + 256 * p) * 8]);
        // compute current tile
        const u16* Sb = S[buf];
        bf16x8 a[2];
#pragma unroll
        for (int m = 0; m < 2; ++m) {
            int row = wr + m * 16 + r;
            a[m] = *(const bf16x8*)&Sb[row * 32 + ((s4 ^ ((row >> 1) & 3)) << 3)];
        }
#pragma unroll
        for (int g = 0; g < 3; ++g)
#pragma unroll
            for (int n = 0; n < 2; ++n) {
                int rowb = 64 + g * 64 + wc + n * 16 + r;
                bf16x8 b = *(const bf16x8*)&Sb[rowb * 32 + ((s4 ^ ((rowb >> 1) & 3)) << 3)];
#pragma unroll
                for (int m = 0; m < 2; ++m)
                    acc[m][g][n] = __builtin_amdgcn_mfma_f32_16x16x32_bf16(a[m], b, acc[m][g][n], 0, 0, 0);
            }
        __syncthreads();   // drains vmcnt (next tile ready) + lgkm
        buf ^= 1;
    }
    {   // final tile: compute only
        const u16* Sb = S[buf];
        bf16x8 a[2];
#pragma unroll
        for (int m = 0; m < 2; ++m) {
            int row = wr + m * 16 + r;
            a[m] = *(const bf16x8*)&Sb[row * 32 + ((s4 ^ ((row >> 1) & 3)) << 3)];
        }
#pragma unroll
        for (int g = 0; g < 3; ++g)
#pragma unroll
            for (int n = 0; n < 2; ++n) {
                int rowb = 64 + g * 64 + wc + n * 16 + r;
                bf16x8 b = *(const bf16x8*)&Sb[rowb * 32 + ((s4 ^ ((rowb >> 1) & 3)) << 3)];
#pragma unroll
                for (int m = 0; m < 2; ++m)
                    acc[m][g][n] = __builtin_amdgcn_mfma_f32_16x16x32_bf16(a[m], b, acc[m][g][n], 0, 0, 0);
            }
    }

    // epilogue: x = relu(G0 + amp*G1 + att*G2 + bias), dual-write
    int gcb = cb * 64 + wc;
#pragma unroll
    for (int m = 0; m < 2; ++m)
#pragma unroll
        for (int j = 0; j < 4; ++j) {
            int grow = row0 + wr + m * 16 + s4 * 4 + j;
            if (grow < NN) {
                float av = amp[grow], tv = att[grow];
#pragma unroll
                for (int n = 0; n < 2; ++n) {
                    int gcol = gcb + n * 16 + r;
                    float v = acc[m][0][n][j] + av * acc[m][1][n][j] + tv * acc[m][2][n][j] + bias[gcol];
                    v = fmaxf(v, 0.f);
                    u16 h = f2bf(v);
                    xout[(size_t)grow * F + gcol] = h;
                    catout[(size_t)grow * CATW + gcol] = h;
                }
            }
        }
}

// ---------------- final output ----------------

__global__ void out_kernel(const u16* __restrict__ x, const float* __restrict__ Wout,
                           const float* __restrict__ bout, float* __restrict__ y) {
    int gid = blockIdx.x * blockDim.x + threadIdx.x;
    int wid = gid >> 6, lane = threadIdx.x & 63;
    if (wid >= NN) return;
    u32 u = *(const u32*)&x[(size_t)wid * F + 2 * lane];
    float v = bflo(u) * Wout[2 * lane] + bfhi(u) * Wout[2 * lane + 1];
#pragma unroll
    for (int o = 32; o > 0; o >>= 1) v += __shfl_down(v, o, 64);
    if (lane == 0) y[wid] = v + bout[0];
}

// ---------------- host ----------------

extern "C" void kernel_launch(void* const* d_in, const int* in_sizes, int n_in,
                              void* d_out, int out_size, void* d_ws, size_t ws_size,
                              hipStream_t stream) {
    const float* x_in   = (const float*)d_in[0];
    const int*   ei     = (const int*)d_in[1];
    const float* W_pre  = (const float*)d_in[2];
    const float* b_pre  = (const float*)d_in[3];
    const float* W_post = (const float*)d_in[4];
    const float* b_post = (const float*)d_in[5];
    const float* W_lin  = (const float*)d_in[6];
    const float* b_lin  = (const float*)d_in[7];
    const float* W_out  = (const float*)d_in[8];
    const float* b_out  = (const float*)d_in[9];

    const int* src = ei;
    const int* dst = ei + NE;

    double sl = 0.0;
    for (int i = 0; i < 33; ++i) sl += log((double)(i + 1));
    float avg_log = (float)(sl / 33.0);

    char* ws = (char*)d_ws;
    size_t p = 0;
    auto alloc = [&](size_t bytes) { void* r = ws + p; p += (bytes + 255) & ~(size_t)255; return r; };
    u16*   cat     = (u16*)alloc((size_t)MPAD * CATW * 2);
    u16*   xbuf    = (u16*)alloc((size_t)MPAD * F * 2);
    u16*   preout  = (u16*)alloc((size_t)MPAD * 256 * 2);
    u16*   WpreT   = (u16*)alloc((size_t)3 * 256 * 128 * 2);
    u16*   Wpostb  = (u16*)alloc((size_t)3 * 2048 * 128 * 2);
    u16*   WlinT   = (u16*)alloc((size_t)3 * 128 * 128 * 2);
    u16*   Btcomb  = (u16*)alloc((size_t)3 * 128 * 2048 * 2);
    u16*   BtK     = (u16*)alloc((size_t)3 * 384 * 768 * 2);
    float* biaspre = (float*)alloc((size_t)3 * 256 * 4);
    float* bcomb   = (float*)alloc((size_t)3 * 128 * 4);
    float* amp     = (float*)alloc((size_t)MPAD * 4);
    float* att     = (float*)alloc((size_t)MPAD * 4);
    int*   cnt     = (int*)alloc((size_t)NN * 4);
    int*   offs    = (int*)alloc((size_t)(NN + 1) * 4);
    int*   cur     = (int*)alloc((size_t)NN * 4);
    int*   csr     = (int*)alloc((size_t)NE * 4);
    int*   bsum    = (int*)alloc((size_t)SCAN_NB * 4);
    (void)ws_size;

    prep_all<<<(int)((P5 + 255) / 256), 256, 0, stream>>>(
        x_in, W_pre, W_lin, W_post, b_pre, b_post, b_lin,
        xbuf, cat, WpreT, WlinT, Wpostb, biaspre, bcomb);

    zero_ints_kernel<<<(NN + 255) / 256, 256, 0, stream>>>(cnt, cur, NN);
    hist_kernel<<<(NE + 255) / 256, 256, 0, stream>>>(dst, cnt, NE);
    scan_p1<<<SCAN_NB, 256, 0, stream>>>(cnt, bsum);
    scan_p2<<<1, 128, 0, stream>>>(bsum);
    scan_p3<<<SCAN_NB, 256, 0, stream>>>(cnt, bsum, offs, amp, att, avg_log);
    scatter_kernel<<<(NE + 255) / 256, 256, 0, stream>>>(src, dst, offs, cur, csr, NE);

    // Btcomb[l] = (W_post@W_lin)^T  [128 x 2048], all 3 layers in one launch
    mfma_gemm<false><<<dim3(2, 16, 3), 256, 0, stream>>>(
        WlinT, 128, Wpostb, 128, nullptr, Btcomb, 2048, 128,
        16384, 262144, 262144);
    brepack_kernel<<<dim3(1152, 3), 256, 0, stream>>>(Btcomb, BtK);

    // layer-0 pre: preout = x @ [Wtop|Wbot] + [b_pre|0]
    mfma_gemm<true><<<dim3(313, 2, 1), 256, 0, stream>>>(
        xbuf, F, WpreT, 128, biaspre, preout, 256, MPAD, 0, 0, 0);

    for (int l = 0; l < NLAYER; ++l) {
        agg_kernel<<<NN, 256, 0, stream>>>(preout, offs, csr, cat);
        comb2<<<dim3(313, 2), 256, 0, stream>>>(
            cat, BtK + (size_t)l * 294912, bcomb + (size_t)l * 128,
            amp, att, xbuf, cat);
        if (l < NLAYER - 1) {
            mfma_gemm<true><<<dim3(313, 2, 1), 256, 0, stream>>>(
                xbuf, F, WpreT + (size_t)(l + 1) * 32768, 128,
                biaspre + (size_t)(l + 1) * 256, preout, 256, MPAD, 0, 0, 0);
        }
    }

    out_kernel<<<5000, 256, 0, stream>>>(xbuf, W_out, b_out, (float*)d_out);
}

// Round 7
// 251.340 us; speedup vs baseline: 1.1110x; 1.0282x over previous
//
#include <hip/hip_runtime.h>
#include <math.h>

#define NN 20000
#define NE 320000
#define F 128
#define NLAYER 3
#define MPAD 20032          // 313 * 64
#define CATW 768            // [x | mean sum std min max]
#define SCAN_NB 79          // ceil(NN/256)

typedef unsigned int u32;
typedef unsigned short u16;
typedef __attribute__((ext_vector_type(8))) short bf16x8;
typedef __attribute__((ext_vector_type(4))) float f32x4;

__device__ __forceinline__ u16 f2bf(float f) {
    union { float f; u32 u; } x{f};
    u32 r = x.u + 0x7FFFu + ((x.u >> 16) & 1u);
    return (u16)(r >> 16);
}
__device__ __forceinline__ float bflo(u32 u) { return __uint_as_float(u << 16); }
__device__ __forceinline__ float bfhi(u32 u) { return __uint_as_float(u & 0xFFFF0000u); }

__device__ __forceinline__ void gload16(const u16* g, u16* l) {
    __builtin_amdgcn_global_load_lds(
        (const __attribute__((address_space(1))) void*)g,
        (__attribute__((address_space(3))) void*)l, 16, 0, 0);
}

// ---------------- graph-structure kernels ----------------

__global__ void hist_kernel(const int* __restrict__ dst, int* __restrict__ cnt, int e) {
    int i = blockIdx.x * blockDim.x + threadIdx.x;
    if (i < e) atomicAdd(&cnt[dst[i]], 1);
}

__global__ void scan_p1(const int* __restrict__ cnt, int* __restrict__ bsum) {
    __shared__ int sh[256];
    int i = blockIdx.x * 256 + threadIdx.x;
    int t = threadIdx.x;
    sh[t] = (i < NN) ? cnt[i] : 0;
    __syncthreads();
#pragma unroll
    for (int d = 128; d > 0; d >>= 1) {
        if (t < d) sh[t] += sh[t + d];
        __syncthreads();
    }
    if (t == 0) bsum[blockIdx.x] = sh[0];
}

__global__ void scan_p2(int* __restrict__ bsum) {
    __shared__ int sh[128];
    int t = threadIdx.x;
    int v = (t < SCAN_NB) ? bsum[t] : 0;
    sh[t] = v;
    __syncthreads();
#pragma unroll
    for (int d = 1; d < 128; d <<= 1) {
        int x = (t >= d) ? sh[t - d] : 0;
        __syncthreads();
        sh[t] += x;
        __syncthreads();
    }
    if (t < SCAN_NB) bsum[t] = sh[t] - v;   // exclusive
}

__global__ void scan_p3(const int* __restrict__ cnt, const int* __restrict__ bsum,
                        int* __restrict__ off, float* __restrict__ amp,
                        float* __restrict__ att, float avg_log) {
    __shared__ int sh[256];
    int i = blockIdx.x * 256 + threadIdx.x;
    int t = threadIdx.x;
    int v = (i < NN) ? cnt[i] : 0;
    sh[t] = v;
    __syncthreads();
#pragma unroll
    for (int d = 1; d < 256; d <<= 1) {
        int x = (t >= d) ? sh[t - d] : 0;
        __syncthreads();
        sh[t] += x;
        __syncthreads();
    }
    if (i < NN) {
        int incl = sh[t] + bsum[blockIdx.x];
        off[i] = incl - v;
        if (i == NN - 1) off[NN] = incl;
        float deg = fmaxf((float)v, 1.0f);
        float ld = logf(deg + 1.0f);
        amp[i] = ld / avg_log;
        att[i] = avg_log / ld;
    }
}

__global__ void scatter_kernel(const int* __restrict__ src, const int* __restrict__ dst,
                               const int* __restrict__ off, int* __restrict__ cur,
                               int* __restrict__ csr, int e) {
    int i = blockIdx.x * blockDim.x + threadIdx.x;
    if (i < e) {
        int d = dst[i];
        int p = atomicAdd(&cur[d], 1);
        csr[off[d] + p] = src[i];
    }
}

// ---------------- combined prep: converts + biases + zero-fills, flat-indexed ----------------

#define P0 2560000L                 // xprep NN*F
#define P1 (P0 + 3L * 256 * 128)    // wpreT
#define P2 (P1 + 3L * 128 * 128)    // wlinT
#define P3 (P2 + 3L * 2048 * 128)   // wpost
#define P4 (P3 + 3L * 256)          // biaspre
#define P5 (P4 + 3L * 128)          // bcomb
#define P6 (P5 + 3L * 2 * 128 * 128) // BtK zero (g=1,2 x-block)
#define P7 (P6 + 2L * NN)           // cnt/cur zero

__global__ void prep_all(const float* __restrict__ x, const float* __restrict__ W_pre,
                         const float* __restrict__ W_lin, const float* __restrict__ W_post,
                         const float* __restrict__ b_pre, const float* __restrict__ b_post,
                         const float* __restrict__ b_lin,
                         u16* __restrict__ xbuf, u16* __restrict__ cat,
                         u16* __restrict__ WpreT, u16* __restrict__ WlinT,
                         u16* __restrict__ Wpostb, float* __restrict__ biaspre,
                         float* __restrict__ bcomb, u16* __restrict__ BtK,
                         int* __restrict__ cnt, int* __restrict__ cur) {
    long i = (long)blockIdx.x * 256 + threadIdx.x;
    if (i < P0) {
        u16 h = f2bf(x[i]);
        xbuf[i] = h;
        cat[(size_t)(i >> 7) * CATW + (i & 127)] = h;
    } else if (i < P1) {
        long j = i - P0;
        int l = j / 32768, t = j % 32768;
        int c = t >> 7, k = t & 127;
        int si = (c < 128) ? (k * 128 + c) : ((k + 128) * 128 + (c - 128));
        WpreT[l * 32768 + t] = f2bf(W_pre[l * 32768 + si]);
    } else if (i < P2) {
        long j = i - P1;
        int l = j / 16384, t = j % 16384;
        int c = t >> 7, k = t & 127;
        WlinT[l * 16384 + t] = f2bf(W_lin[l * 16384 + k * 128 + c]);
    } else if (i < P3) {
        long j = i - P2;
        Wpostb[j] = f2bf(W_post[j]);
    } else if (i < P4) {
        long j = i - P3;
        int l = j / 256, t = j % 256;
        biaspre[l * 256 + t] = (t < 128) ? b_pre[l * 128 + t] : 0.f;
    } else if (i < P5) {
        long j = i - P4;
        int l = j / 128, t = j % 128;
        float s = b_lin[l * 128 + t];
        for (int c = 0; c < 128; ++c) s += b_post[l * 128 + c] * W_lin[l * 16384 + c * 128 + t];
        bcomb[l * 128 + t] = s;
    } else if (i < P6) {
        long j = i - P5;
        int l = j / 32768, t = j % 32768;
        int gg = 1 + (t >> 14);
        int row = (t >> 7) & 127, k = t & 127;
        BtK[(size_t)l * 294912 + (size_t)(gg * 128 + row) * 768 + k] = 0;
    } else if (i < P7) {
        long j = i - P6;
        if (j < NN) cnt[j] = 0; else cur[j - NN] = 0;
    }
}

// ---------------- aggregation: one block (4 waves) per node, 4 gathers in flight ----------------

#define PROC(u) { float v_; \
    v_ = bflo(u); s0 += v_; q0 = fmaf(v_, v_, q0); mn0 = fminf(mn0, v_); mx0 = fmaxf(mx0, v_); \
    v_ = bfhi(u); s1 += v_; q1 = fmaf(v_, v_, q1); mn1 = fminf(mn1, v_); mx1 = fmaxf(mx1, v_); }

__global__ __launch_bounds__(256) void agg_kernel(
    const u16* __restrict__ preout, const int* __restrict__ off,
    const int* __restrict__ csr, u16* __restrict__ cat) {
    int node = blockIdx.x;
    int tid = threadIdx.x, w = tid >> 6, lane = tid & 63;
    int o0 = off[node], o1 = off[node + 1];
    const u32* bpl = (const u32*)preout + 64 + lane;   // row stride 128 u32
    float s0 = 0, s1 = 0, q0 = 0, q1 = 0;
    float mn0 = 1e30f, mn1 = 1e30f, mx0 = -1e30f, mx1 = -1e30f;
    int j = o0 + w;
    for (; j + 12 < o1; j += 16) {
        int i0 = csr[j], i1 = csr[j + 4], i2 = csr[j + 8], i3 = csr[j + 12];
        u32 u0 = bpl[(size_t)i0 * 128];
        u32 u1 = bpl[(size_t)i1 * 128];
        u32 u2 = bpl[(size_t)i2 * 128];
        u32 u3 = bpl[(size_t)i3 * 128];
        PROC(u0); PROC(u1); PROC(u2); PROC(u3);
    }
    for (; j < o1; j += 4) { u32 u = bpl[(size_t)csr[j] * 128]; PROC(u); }

    __shared__ float red[8][256];
    red[0][tid] = s0; red[1][tid] = s1; red[2][tid] = q0; red[3][tid] = q1;
    red[4][tid] = mn0; red[5][tid] = mn1; red[6][tid] = mx0; red[7][tid] = mx1;
    __syncthreads();
    if (w != 0) return;

    s0 = 0; s1 = 0; q0 = 0; q1 = 0;
    mn0 = 1e30f; mn1 = 1e30f; mx0 = -1e30f; mx1 = -1e30f;
#pragma unroll
    for (int ww = 0; ww < 4; ++ww) {
        int sl = ww * 64 + lane;
        s0 += red[0][sl]; s1 += red[1][sl];
        q0 += red[2][sl]; q1 += red[3][sl];
        mn0 = fminf(mn0, red[4][sl]); mn1 = fminf(mn1, red[5][sl]);
        mx0 = fmaxf(mx0, red[6][sl]); mx1 = fmaxf(mx1, red[7][sl]);
    }

    int degi = o1 - o0;
    float mean0, mean1, sum0, sum1, std0, std1, lo0, lo1, hi0, hi1;
    if (degi == 0) {
        sum0 = sum1 = 0.f; mean0 = mean1 = 0.f;
        std0 = std1 = sqrtf(1e-5f);
        lo0 = lo1 = hi0 = hi1 = 0.f;
    } else {
        u32 uc = ((const u32*)preout)[(size_t)node * 128 + lane];
        float c0 = bflo(uc), c1 = bfhi(uc), dg = (float)degi;
        sum0 = dg * c0 + s0; mean0 = sum0 / dg;
        sum1 = dg * c1 + s1; mean1 = sum1 / dg;
        float msq0 = c0 * c0 + (2.f * c0 * s0 + q0) / dg;
        float msq1 = c1 * c1 + (2.f * c1 * s1 + q1) / dg;
        std0 = sqrtf(fmaxf(msq0 - mean0 * mean0, 0.f) + 1e-5f);
        std1 = sqrtf(fmaxf(msq1 - mean1 * mean1, 0.f) + 1e-5f);
        lo0 = c0 + mn0; lo1 = c1 + mn1; hi0 = c0 + mx0; hi1 = c1 + mx1;
    }
    u32* cr = (u32*)cat + (size_t)node * (CATW / 2) + 64 + lane;
    float f0[5] = {mean0, sum0, std0, lo0, hi0};
    float f1[5] = {mean1, sum1, std1, lo1, hi1};
#pragma unroll
    for (int a = 0; a < 5; ++a)
        cr[a * 64] = (u32)f2bf(f0[a]) | ((u32)f2bf(f1[a]) << 16);
}

// ---------------- generic bf16 MFMA GEMM ----------------
// MODE 0: C[grow*ldc+gcol]. MODE 1: scatter into BtK layout (wprod).
// SWZ: 1D grid 640, XCD-paired (row, col-half) decomposition.

template <bool BIAS, int MODE, bool SWZ>
__global__ __launch_bounds__(256) void mfma_gemm(
    const u16* __restrict__ A, int lda,
    const u16* __restrict__ Bt, int K,
    const float* __restrict__ bias,
    u16* __restrict__ C, int ldc, int Mreal,
    size_t aS, size_t bS, size_t cS) {
    __shared__ u16 As[64 * 32];
    __shared__ u16 Bs[128 * 32];
    int row0, col0;
    if (SWZ) {
        int g = blockIdx.x;
        int row = (g >> 4) * 8 + (g & 7);
        if (row >= 313) return;
        row0 = row * 64;
        col0 = ((g >> 3) & 1) * 128;
    } else {
        row0 = blockIdx.x * 64;
        col0 = blockIdx.y * 128;
    }
    int z = blockIdx.z;
    A += (size_t)z * aS; Bt += (size_t)z * bS; C += (size_t)z * cS;
    int tid = threadIdx.x;
    int w = tid >> 6, lane = tid & 63;

    int arow = tid >> 2, asl = tid & 3;
    const u16* agp = A + (size_t)(row0 + arow) * lda + ((asl ^ ((arow >> 1) & 3)) << 3);
    u16* alds = As + w * 512;
    int br0 = tid >> 2;
    int br1 = 64 + (tid >> 2);
    const u16* bgp0 = Bt + (size_t)(col0 + br0) * K + (((tid & 3) ^ ((br0 >> 1) & 3)) << 3);
    const u16* bgp1 = Bt + (size_t)(col0 + br1) * K + (((tid & 3) ^ ((br1 >> 1) & 3)) << 3);
    u16* blds0 = Bs + w * 512;
    u16* blds1 = Bs + 2048 + w * 512;

    f32x4 acc[2][4];
#pragma unroll
    for (int m = 0; m < 2; ++m)
#pragma unroll
        for (int n = 0; n < 4; ++n) acc[m][n] = (f32x4){0.f, 0.f, 0.f, 0.f};

    int s = lane >> 4, r = lane & 15;
    int wr = (w >> 1) * 32, wc = (w & 1) * 64;

    for (int k0 = 0; k0 < K; k0 += 32) {
        gload16(agp + k0, alds);
        gload16(bgp0 + k0, blds0);
        gload16(bgp1 + k0, blds1);
        __syncthreads();
        bf16x8 a[2], b[4];
#pragma unroll
        for (int m = 0; m < 2; ++m) {
            int row = wr + m * 16 + r;
            a[m] = *(const bf16x8*)&As[row * 32 + ((s ^ ((row >> 1) & 3)) << 3)];
        }
#pragma unroll
        for (int n = 0; n < 4; ++n) {
            int col = wc + n * 16 + r;
            b[n] = *(const bf16x8*)&Bs[col * 32 + ((s ^ ((col >> 1) & 3)) << 3)];
        }
#pragma unroll
        for (int m = 0; m < 2; ++m)
#pragma unroll
            for (int n = 0; n < 4; ++n)
                acc[m][n] = __builtin_amdgcn_mfma_f32_16x16x32_bf16(a[m], b[n], acc[m][n], 0, 0, 0);
        __syncthreads();
    }

#pragma unroll
    for (int m = 0; m < 2; ++m) {
#pragma unroll
        for (int n = 0; n < 4; ++n) {
            int gcol = col0 + wc + n * 16 + r;
            float bs = BIAS ? bias[gcol] : 0.f;
#pragma unroll
            for (int j = 0; j < 4; ++j) {
                int grow = row0 + wr + m * 16 + s * 4 + j;
                if (grow < Mreal) {
                    u16 h = f2bf(acc[m][n][j] + bs);
                    if (MODE == 0) {
                        C[(size_t)grow * ldc + gcol] = h;
                    } else {
                        size_t idx;
                        if (gcol < 128) idx = (size_t)grow * 768 + gcol;
                        else {
                            int t2 = gcol - 128;
                            int gg = t2 / 640;
                            int ko = 128 + t2 - gg * 640;
                            idx = (size_t)(gg * 128 + grow) * 768 + ko;
                        }
                        C[idx] = h;
                    }
                }
            }
        }
    }
}

// ---------------- comb2: depth-2 counted-vmcnt pipelined comb GEMM ----------------
// grid 640 (XCD-paired), 256 threads (4 waves). Tile 64 rows x 64 out-cols x 3 groups.
// K-step 32, 3 LDS buffers (48 KB). STAGE(t+2) in flight; s_waitcnt vmcnt(4) + raw barrier.

__global__ __launch_bounds__(256) void comb2(
    const u16* __restrict__ A,          // cat [MPAD][768]
    const u16* __restrict__ BtK,        // [384][768], row = g*128 + outcol
    const float* __restrict__ bias,     // bcomb 128
    const float* __restrict__ amp, const float* __restrict__ att,
    u16* __restrict__ xout,             // xbuf [MPAD][128]
    u16* __restrict__ catout) {         // cat cols 0..127
    __shared__ u16 S[3][8192];          // 3 x 16 KB
    int g = blockIdx.x;
    int row = (g >> 4) * 8 + (g & 7);
    if (row >= 313) return;
    int row0 = row * 64;
    int cb = (g >> 3) & 1;              // 64-col half
    int tid = threadIdx.x;
    int w = tid >> 6, lane = tid & 63;
    int r = lane & 15, s4 = lane >> 4;
    int wr = (w >> 1) * 32, wc = (w & 1) * 32;

    const u16* gp[4];
#pragma unroll
    for (int p = 0; p < 4; ++p) {
        int lid = tid + 256 * p;
        int rt = lid >> 2, q = lid & 3;
        int koff = (q ^ ((rt >> 1) & 3)) << 3;     // pre-swizzled source
        if (rt < 64) gp[p] = A + (size_t)(row0 + rt) * 768 + koff;
        else {
            int rb = rt - 64, gg = rb >> 6, jj = rb & 63;
            gp[p] = BtK + (size_t)(gg * 128 + cb * 64 + jj) * 768 + koff;
        }
    }

    f32x4 acc[2][3][2];
#pragma unroll
    for (int m = 0; m < 2; ++m)
#pragma unroll
        for (int gg = 0; gg < 3; ++gg)
#pragma unroll
            for (int n = 0; n < 2; ++n) acc[m][gg][n] = (f32x4){0.f, 0.f, 0.f, 0.f};

    auto STAGE = [&](int t, int b) {
#pragma unroll
        for (int p = 0; p < 4; ++p)
            gload16(gp[p] + t * 32, &S[b][(size_t)(tid + 256 * p) * 8]);
    };

    // prologue: tiles 0 and 1 in flight
    STAGE(0, 0);
    STAGE(1, 1);
    asm volatile("s_waitcnt vmcnt(4)" ::: "memory");   // tile 0 complete
    __builtin_amdgcn_s_barrier();
    asm volatile("" ::: "memory");

    int buf = 0;
    for (int t = 0; t < 24; ++t) {
        if (t + 2 < 24) STAGE(t + 2, (t + 2) % 3);
        const u16* Sb = S[buf];
        bf16x8 a[2];
#pragma unroll
        for (int m = 0; m < 2; ++m) {
            int rw = wr + m * 16 + r;
            a[m] = *(const bf16x8*)&Sb[rw * 32 + ((s4 ^ ((rw >> 1) & 3)) << 3)];
        }
#pragma unroll
        for (int gg = 0; gg < 3; ++gg)
#pragma unroll
            for (int n = 0; n < 2; ++n) {
                int rowb = 64 + gg * 64 + wc + n * 16 + r;
                bf16x8 b = *(const bf16x8*)&Sb[rowb * 32 + ((s4 ^ ((rowb >> 1) & 3)) << 3)];
#pragma unroll
                for (int m = 0; m < 2; ++m)
                    acc[m][gg][n] = __builtin_amdgcn_mfma_f32_16x16x32_bf16(a[m], b, acc[m][gg][n], 0, 0, 0);
            }
        if (t < 23) {
            if (t + 2 < 24) asm volatile("s_waitcnt vmcnt(4)" ::: "memory");  // next tile done
            else            asm volatile("s_waitcnt vmcnt(0)" ::: "memory");
            __builtin_amdgcn_s_barrier();
            asm volatile("" ::: "memory");
        }
        buf = (buf == 2) ? 0 : buf + 1;
    }

    // epilogue: x = relu(G0 + amp*G1 + att*G2 + bias), dual-write
    int gcb = cb * 64 + wc;
#pragma unroll
    for (int m = 0; m < 2; ++m)
#pragma unroll
        for (int j = 0; j < 4; ++j) {
            int grow = row0 + wr + m * 16 + s4 * 4 + j;
            if (grow < NN) {
                float av = amp[grow], tv = att[grow];
#pragma unroll
                for (int n = 0; n < 2; ++n) {
                    int gcol = gcb + n * 16 + r;
                    float v = acc[m][0][n][j] + av * acc[m][1][n][j] + tv * acc[m][2][n][j] + bias[gcol];
                    v = fmaxf(v, 0.f);
                    u16 h = f2bf(v);
                    xout[(size_t)grow * F + gcol] = h;
                    catout[(size_t)grow * CATW + gcol] = h;
                }
            }
        }
}

// ---------------- final output ----------------

__global__ void out_kernel(const u16* __restrict__ x, const float* __restrict__ Wout,
                           const float* __restrict__ bout, float* __restrict__ y) {
    int gid = blockIdx.x * blockDim.x + threadIdx.x;
    int wid = gid >> 6, lane = threadIdx.x & 63;
    if (wid >= NN) return;
    u32 u = *(const u32*)&x[(size_t)wid * F + 2 * lane];
    float v = bflo(u) * Wout[2 * lane] + bfhi(u) * Wout[2 * lane + 1];
#pragma unroll
    for (int o = 32; o > 0; o >>= 1) v += __shfl_down(v, o, 64);
    if (lane == 0) y[wid] = v + bout[0];
}

// ---------------- host ----------------

extern "C" void kernel_launch(void* const* d_in, const int* in_sizes, int n_in,
                              void* d_out, int out_size, void* d_ws, size_t ws_size,
                              hipStream_t stream) {
    const float* x_in   = (const float*)d_in[0];
    const int*   ei     = (const int*)d_in[1];
    const float* W_pre  = (const float*)d_in[2];
    const float* b_pre  = (const float*)d_in[3];
    const float* W_post = (const float*)d_in[4];
    const float* b_post = (const float*)d_in[5];
    const float* W_lin  = (const float*)d_in[6];
    const float* b_lin  = (const float*)d_in[7];
    const float* W_out  = (const float*)d_in[8];
    const float* b_out  = (const float*)d_in[9];

    const int* src = ei;
    const int* dst = ei + NE;

    double sl = 0.0;
    for (int i = 0; i < 33; ++i) sl += log((double)(i + 1));
    float avg_log = (float)(sl / 33.0);

    char* ws = (char*)d_ws;
    size_t p = 0;
    auto alloc = [&](size_t bytes) { void* r = ws + p; p += (bytes + 255) & ~(size_t)255; return r; };
    u16*   cat     = (u16*)alloc((size_t)MPAD * CATW * 2);
    u16*   xbuf    = (u16*)alloc((size_t)MPAD * F * 2);
    u16*   preout  = (u16*)alloc((size_t)MPAD * 256 * 2);
    u16*   WpreT   = (u16*)alloc((size_t)3 * 256 * 128 * 2);
    u16*   Wpostb  = (u16*)alloc((size_t)3 * 2048 * 128 * 2);
    u16*   WlinT   = (u16*)alloc((size_t)3 * 128 * 128 * 2);
    u16*   BtK     = (u16*)alloc((size_t)3 * 384 * 768 * 2);
    float* biaspre = (float*)alloc((size_t)3 * 256 * 4);
    float* bcomb   = (float*)alloc((size_t)3 * 128 * 4);
    float* amp     = (float*)alloc((size_t)MPAD * 4);
    float* att     = (float*)alloc((size_t)MPAD * 4);
    int*   cnt     = (int*)alloc((size_t)NN * 4);
    int*   offs    = (int*)alloc((size_t)(NN + 1) * 4);
    int*   cur     = (int*)alloc((size_t)NN * 4);
    int*   csr     = (int*)alloc((size_t)NE * 4);
    int*   bsum    = (int*)alloc((size_t)SCAN_NB * 4);
    (void)ws_size;

    prep_all<<<(int)((P7 + 255) / 256), 256, 0, stream>>>(
        x_in, W_pre, W_lin, W_post, b_pre, b_post, b_lin,
        xbuf, cat, WpreT, WlinT, Wpostb, biaspre, bcomb, BtK, cnt, cur);

    hist_kernel<<<(NE + 255) / 256, 256, 0, stream>>>(dst, cnt, NE);
    scan_p1<<<SCAN_NB, 256, 0, stream>>>(cnt, bsum);
    scan_p2<<<1, 128, 0, stream>>>(bsum);
    scan_p3<<<SCAN_NB, 256, 0, stream>>>(cnt, bsum, offs, amp, att, avg_log);
    scatter_kernel<<<(NE + 255) / 256, 256, 0, stream>>>(src, dst, offs, cur, csr, NE);

    // BtK[l] = (W_post@W_lin)^T scattered into [384][768] layout, all 3 layers
    mfma_gemm<false, 1, false><<<dim3(2, 16, 3), 256, 0, stream>>>(
        WlinT, 128, Wpostb, 128, nullptr, BtK, 0, 128,
        16384, 262144, 294912);

    // layer-0 pre: preout = x @ [Wtop|Wbot] + [b_pre|0]
    mfma_gemm<true, 0, true><<<640, 256, 0, stream>>>(
        xbuf, F, WpreT, 128, biaspre, preout, 256, MPAD, 0, 0, 0);

    for (int l = 0; l < NLAYER; ++l) {
        agg_kernel<<<NN, 256, 0, stream>>>(preout, offs, csr, cat);
        comb2<<<640, 256, 0, stream>>>(
            cat, BtK + (size_t)l * 294912, bcomb + (size_t)l * 128,
            amp, att, xbuf, cat);
        if (l < NLAYER - 1) {
            mfma_gemm<true, 0, true><<<640, 256, 0, stream>>>(
                xbuf, F, WpreT + (size_t)(l + 1) * 32768, 128,
                biaspre + (size_t)(l + 1) * 256, preout, 256, MPAD, 0, 0, 0);
        }
    }

    out_kernel<<<5000, 256, 0, stream>>>(xbuf, W_out, b_out, (float*)d_out);
}